// Round 1
// baseline (328.112 us; speedup 1.0000x reference)
//
#include <hip/hip_runtime.h>

#define P_PTS   1024
#define NN      32
#define NA      60
#define KS      24
#define CIN     32
#define COUT    64
#define AC      12          // anchors per chunk in main kernel
#define NCH     5           // 60 / 12
#define NFS     (CIN*KS + 4)   // 772, padded leading dim for nf

// ---------------------------------------------------------------------------
// Kernel A: ball query. One wave (64 lanes) per query point; ballot-based
// ordered selection of the first NN indices (ascending) with d2 < 1.0,
// padded with the first valid index. Writes idx[p][NN] and rel[p][NN][3].
// ---------------------------------------------------------------------------
__global__ __launch_bounds__(256) void ball_query_kernel(
    const float* __restrict__ xyz, int* __restrict__ ws_idx,
    float* __restrict__ ws_rel)
{
  __shared__ float sx[P_PTS], sy[P_PTS], sz[P_PTS], sq[P_PTS];
  __shared__ int s_loc[4][NN];
  const int tid = threadIdx.x;

  for (int i = tid; i < P_PTS; i += 256) {
    float x = xyz[i], y = xyz[P_PTS + i], z = xyz[2*P_PTS + i];
    sx[i] = x; sy[i] = y; sz[i] = z;
    sq[i] = x*x + y*y + z*z;
  }
  __syncthreads();

  const int wave = tid >> 6;
  const int lane = tid & 63;
  const int q = blockIdx.x * 4 + wave;

  const float xq = sx[q], yq = sy[q], zq = sz[q], sqq = sq[q];
  int cnt = 0;
  for (int jb = 0; jb < P_PTS; jb += 64) {
    const int j = jb + lane;
    // same formula as reference: sq[q] + sq[j] - 2*dot
    const float d2 = sqq + sq[j] - 2.0f*(xq*sx[j] + yq*sy[j] + zq*sz[j]);
    const bool pred = d2 < 1.0f;            // RADIUS^2 = 1
    const unsigned long long mask = __ballot(pred);
    if (pred) {
      const int slot = cnt + __popcll(mask & ((1ull << lane) - 1ull));
      if (slot < NN) s_loc[wave][slot] = j;
    }
    cnt += (int)__popcll(mask);
    if (cnt >= NN) break;
  }
  __syncthreads();
  // pad with first valid (self always valid -> cnt >= 1)
  const int cntc = cnt < NN ? cnt : NN;
  if (lane >= cntc && lane < NN) s_loc[wave][lane] = s_loc[wave][0];
  __syncthreads();

  if (lane < NN) {
    const int jj = s_loc[wave][lane];
    ws_idx[q*NN + lane] = jj;
    ws_rel[(q*NN + lane)*3 + 0] = sx[jj] - xq;
    ws_rel[(q*NN + lane)*3 + 1] = sy[jj] - yq;
    ws_rel[(q*NN + lane)*3 + 2] = sz[jj] - zq;
  }
}

// ---------------------------------------------------------------------------
// Kernel B: rotated kernel points rk[a][k][3] = anchors[a] @ kernels[k],
// plus |rk|^2.
// ---------------------------------------------------------------------------
__global__ __launch_bounds__(256) void rk_kernel(
    const float* __restrict__ anchors, const float* __restrict__ kernels,
    float* __restrict__ ws_rk, float* __restrict__ ws_rk2)
{
  const int t = blockIdx.x * 256 + threadIdx.x;
  if (t < NA*KS) {
    const int a = t / KS, k = t - a*KS;
    float s2 = 0.0f;
    #pragma unroll
    for (int i = 0; i < 3; ++i) {
      const float v = anchors[a*9 + i*3 + 0]*kernels[k*3 + 0]
                    + anchors[a*9 + i*3 + 1]*kernels[k*3 + 1]
                    + anchors[a*9 + i*3 + 2]*kernels[k*3 + 2];
      ws_rk[t*3 + i] = v;
      s2 += v*v;
    }
    ws_rk2[t] = s2;
  }
}

// ---------------------------------------------------------------------------
// Kernel C: fused main. Block = (point p, chunk of AC=12 anchors).
// Phase 1: w[n][k][ac] in LDS.  Phase 2: nf[c][k][ac] in registers via
// double-buffered per-neighbor feature gather.  Phase 3: nf -> LDS
// (aliasing the w buffer) and 64x768 GEMM against W.
// ---------------------------------------------------------------------------
__global__ __launch_bounds__(256) void conv_main(
    const float* __restrict__ feats, const float* __restrict__ Wm,
    const float* __restrict__ ws_rel, const int* __restrict__ ws_idx,
    const float* __restrict__ ws_rk, const float* __restrict__ ws_rk2,
    float* __restrict__ out)
{
  const int p   = blockIdx.x;
  const int a0  = blockIdx.y * AC;
  const int tid = threadIdx.x;

  __shared__ __align__(16) float s_big[AC*NFS];     // 9264 fl: w[n][k][ac] then nf[ac][NFS]
  __shared__ __align__(16) float s_gfn[2][CIN*AC];  // double-buffered gathered feats
  __shared__ float s_relx[NN], s_rely[NN], s_relz[NN], s_rel2[NN];
  __shared__ int   s_idx[NN];
  __shared__ float s_rk[AC*KS*3];
  __shared__ float s_rk2[AC*KS];

  // ---- phase 0: load per-point and per-chunk small data ----
  if (tid < NN) {
    const float rx = ws_rel[(p*NN + tid)*3 + 0];
    const float ry = ws_rel[(p*NN + tid)*3 + 1];
    const float rz = ws_rel[(p*NN + tid)*3 + 2];
    s_relx[tid] = rx; s_rely[tid] = ry; s_relz[tid] = rz;
    s_rel2[tid] = rx*rx + ry*ry + rz*rz;
    s_idx[tid] = ws_idx[p*NN + tid];
  }
  for (int e = tid; e < AC*KS*3; e += 256) s_rk[e]  = ws_rk[a0*KS*3 + e];
  for (int e = tid; e < AC*KS;   e += 256) s_rk2[e] = ws_rk2[a0*KS + e];
  __syncthreads();

  // ---- stage neighbor 0 features + phase 1: w weights ----
  const int c_s   = tid / 6;          // staging: channel
  const int ac2_s = (tid - c_s*6)*2;  // staging: anchor pair
  if (tid < (CIN*AC)/2) {
    const float2 v = *(const float2*)&feats[c_s*(P_PTS*NA) + s_idx[0]*NA + a0 + ac2_s];
    *(float2*)&s_gfn[0][c_s*AC + ac2_s] = v;
  }
  for (int e = tid; e < NN*KS*AC; e += 256) {
    const int n  = e / (KS*AC);
    const int r  = e - n*(KS*AC);
    const int k  = r / AC;
    const int ac = r - k*AC;
    const float rkx = s_rk[(ac*KS + k)*3 + 0];
    const float rky = s_rk[(ac*KS + k)*3 + 1];
    const float rkz = s_rk[(ac*KS + k)*3 + 2];
    const float d2 = s_rel2[n] + s_rk2[ac*KS + k]
        - 2.0f*(rkx*s_relx[n] + rky*s_rely[n] + rkz*s_relz[n]);
    s_big[e] = fmaxf(0.0f, 1.0f - d2 * (1.0f/0.16f));   // relu(1 - d2/sigma)
  }
  __syncthreads();

  // ---- phase 2: nf accumulation over neighbors ----
  const int kb = tid & 7;   // k base (k = kb + 8j)
  const int cc = tid >> 3;  // channel 0..31
  float acc[3][12];
  #pragma unroll
  for (int j = 0; j < 3; ++j)
    #pragma unroll
    for (int m = 0; m < 12; ++m) acc[j][m] = 0.0f;

  for (int n = 0; n < NN; ++n) {
    float2 pre;
    const bool doPre = (tid < (CIN*AC)/2) && (n + 1 < NN);
    if (doPre)
      pre = *(const float2*)&feats[c_s*(P_PTS*NA) + s_idx[n+1]*NA + a0 + ac2_s];

    float g[12];
    const float* grow = &s_gfn[n & 1][cc*AC];
    #pragma unroll
    for (int m = 0; m < 12; m += 4) *(float4*)&g[m] = *(const float4*)&grow[m];
    const float* wrow = &s_big[n*(KS*AC)];
    #pragma unroll
    for (int j = 0; j < 3; ++j) {
      const float* wr = &wrow[(kb + 8*j)*AC];
      #pragma unroll
      for (int m = 0; m < 12; m += 4) {
        const float4 wv = *(const float4*)&wr[m];
        acc[j][m+0] = fmaf(g[m+0], wv.x, acc[j][m+0]);
        acc[j][m+1] = fmaf(g[m+1], wv.y, acc[j][m+1]);
        acc[j][m+2] = fmaf(g[m+2], wv.z, acc[j][m+2]);
        acc[j][m+3] = fmaf(g[m+3], wv.w, acc[j][m+3]);
      }
    }
    if (doPre) *(float2*)&s_gfn[(n+1) & 1][c_s*AC + ac2_s] = pre;
    __syncthreads();
  }

  // ---- phase 3a: nf -> LDS as [ac][c*KS + k], stride NFS (aliases w) ----
  #pragma unroll
  for (int j = 0; j < 3; ++j) {
    const int k = kb + 8*j;
    #pragma unroll
    for (int m = 0; m < 12; ++m)
      s_big[m*NFS + cc*KS + k] = acc[j][m];
  }
  __syncthreads();

  // ---- phase 3b: out[o][a] = W[o][:] . nf[:][a] ----
  const int o     = tid >> 2;
  const int aslot = tid & 3;
  float oacc0 = 0.0f, oacc1 = 0.0f, oacc2 = 0.0f;
  const float4* W4  = (const float4*)(Wm + o*(CIN*KS));
  const float4* nf0 = (const float4*)&s_big[(aslot    )*NFS];
  const float4* nf1 = (const float4*)&s_big[(aslot + 4)*NFS];
  const float4* nf2 = (const float4*)&s_big[(aslot + 8)*NFS];
  for (int t4 = 0; t4 < (CIN*KS)/4; ++t4) {
    const float4 wv = W4[t4];
    const float4 v0 = nf0[t4];
    const float4 v1 = nf1[t4];
    const float4 v2 = nf2[t4];
    oacc0 += wv.x*v0.x + wv.y*v0.y + wv.z*v0.z + wv.w*v0.w;
    oacc1 += wv.x*v1.x + wv.y*v1.y + wv.z*v1.z + wv.w*v1.w;
    oacc2 += wv.x*v2.x + wv.y*v2.y + wv.z*v2.z + wv.w*v2.w;
  }
  out[(o*P_PTS + p)*NA + a0 + aslot    ] = oacc0;
  out[(o*P_PTS + p)*NA + a0 + aslot + 4] = oacc1;
  out[(o*P_PTS + p)*NA + a0 + aslot + 8] = oacc2;
}

// ---------------------------------------------------------------------------
extern "C" void kernel_launch(void* const* d_in, const int* in_sizes, int n_in,
                              void* d_out, int out_size, void* d_ws, size_t ws_size,
                              hipStream_t stream) {
  const float* xyz     = (const float*)d_in[0];   // [1,3,1024]
  const float* feats   = (const float*)d_in[1];   // [1,32,1024,60]
  const float* Wm      = (const float*)d_in[2];   // [64,768]
  const float* anchors = (const float*)d_in[3];   // [60,3,3]
  const float* kernels = (const float*)d_in[4];   // [24,3]
  float* out = (float*)d_out;

  // workspace layout (floats): idx | rel | rk | rk2   (~543 KB total)
  float* wsf    = (float*)d_ws;
  int*   ws_idx = (int*)d_ws;                       // 1024*32 ints
  float* ws_rel = wsf + P_PTS*NN;                   // 1024*32*3 floats
  float* ws_rk  = ws_rel + P_PTS*NN*3;              // 60*24*3 floats
  float* ws_rk2 = ws_rk + NA*KS*3;                  // 60*24 floats

  hipLaunchKernelGGL(ball_query_kernel, dim3(P_PTS/4), dim3(256), 0, stream,
                     xyz, ws_idx, ws_rel);
  hipLaunchKernelGGL(rk_kernel, dim3((NA*KS + 255)/256), dim3(256), 0, stream,
                     anchors, kernels, ws_rk, ws_rk2);
  hipLaunchKernelGGL(conv_main, dim3(P_PTS, NCH), dim3(256), 0, stream,
                     feats, Wm, ws_rel, ws_idx, ws_rk, ws_rk2, out);
}

// Round 2
// 196.772 us; speedup vs baseline: 1.6675x; 1.6675x over previous
//
#include <hip/hip_runtime.h>

typedef __attribute__((ext_vector_type(8))) short short8;
typedef __attribute__((ext_vector_type(4))) float f32x4;

#define P_PTS   1024
#define NN      32
#define NA      60
#define KS      24
#define CIN     32
#define COUT    64
#define AC      12          // anchors per chunk
#define NCH     5           // 60 / 12

// LDS short-buffer layout (element offsets, shorts):
//   gf region:  [ac][c][n]  stride 40  -> ac*1280 + c*40 + n      (12*32*40 = 15360)
//   (aliased by nf after contraction 1: [ac][ck] stride 776 -> ac*776 + ck, 16*776 = 12416 <= 15360)
//   w  region:  [ac][k][n]  stride 40  -> 15360 + ac*960 + k*40 + n (12*24*40 = 11520)
#define GF_OFF(ac,c,n)  ((ac)*1280 + (c)*40 + (n))
#define W_OFF(ac,k,n)   (15360 + (ac)*960 + (k)*40 + (n))
#define NF_OFF(ac,ck)   ((ac)*776 + (ck))
#define SBUF_SHORTS     26880

__device__ __forceinline__ unsigned short f2bf(float f) {
  unsigned int u = __float_as_uint(f);
  u += 0x7FFFu + ((u >> 16) & 1u);          // round-to-nearest-even
  return (unsigned short)(u >> 16);
}

// ---------------------------------------------------------------------------
// Ball query: one wave per query point; ordered ballot selection of first NN
// indices (ascending) with d2 < 1, padded with first valid. Writes idx only.
// ---------------------------------------------------------------------------
__global__ __launch_bounds__(256) void ball_query_kernel(
    const float* __restrict__ xyz, int* __restrict__ ws_idx)
{
  __shared__ float sx[P_PTS], sy[P_PTS], sz[P_PTS], sq[P_PTS];
  __shared__ int s_loc[4][NN];
  const int tid = threadIdx.x;

  for (int i = tid; i < P_PTS; i += 256) {
    float x = xyz[i], y = xyz[P_PTS + i], z = xyz[2*P_PTS + i];
    sx[i] = x; sy[i] = y; sz[i] = z;
    sq[i] = x*x + y*y + z*z;
  }
  __syncthreads();

  const int wave = tid >> 6;
  const int lane = tid & 63;
  const int q = blockIdx.x * 4 + wave;

  const float xq = sx[q], yq = sy[q], zq = sz[q], sqq = sq[q];
  int cnt = 0;
  for (int jb = 0; jb < P_PTS; jb += 64) {
    const int j = jb + lane;
    const float d2 = sqq + sq[j] - 2.0f*(xq*sx[j] + yq*sy[j] + zq*sz[j]);
    const bool pred = d2 < 1.0f;
    const unsigned long long mask = __ballot(pred);
    if (pred) {
      const int slot = cnt + __popcll(mask & ((1ull << lane) - 1ull));
      if (slot < NN) s_loc[wave][slot] = j;
    }
    cnt += (int)__popcll(mask);
    if (cnt >= NN) break;
  }
  __syncthreads();
  const int cntc = cnt < NN ? cnt : NN;
  if (lane >= cntc && lane < NN) s_loc[wave][lane] = s_loc[wave][0];
  __syncthreads();
  if (lane < NN) ws_idx[q*NN + lane] = s_loc[wave][lane];
}

// ---------------------------------------------------------------------------
// Prep: W -> bf16, rotated kernel points rk + |rk|^2.
// ---------------------------------------------------------------------------
__global__ __launch_bounds__(256) void prep_kernel(
    const float* __restrict__ Wm, const float* __restrict__ anchors,
    const float* __restrict__ kernels, unsigned short* __restrict__ wbf,
    float* __restrict__ ws_rk, float* __restrict__ ws_rk2)
{
  const int t = blockIdx.x * 256 + threadIdx.x;
  if (t < COUT*CIN*KS) wbf[t] = f2bf(Wm[t]);
  const int u = t - COUT*CIN*KS;
  if (u >= 0 && u < NA*KS) {
    const int a = u / KS, k = u - a*KS;
    float s2 = 0.0f;
    #pragma unroll
    for (int i = 0; i < 3; ++i) {
      const float v = anchors[a*9 + i*3 + 0]*kernels[k*3 + 0]
                    + anchors[a*9 + i*3 + 1]*kernels[k*3 + 1]
                    + anchors[a*9 + i*3 + 2]*kernels[k*3 + 2];
      ws_rk[u*3 + i] = v;
      s2 += v*v;
    }
    ws_rk2[u] = s2;
  }
}

// ---------------------------------------------------------------------------
// Main fused kernel, MFMA version. Block = (point p, chunk of 12 anchors).
// ---------------------------------------------------------------------------
__global__ __launch_bounds__(256, 2) void conv_mfma(
    const float* __restrict__ xyz, const float* __restrict__ feats,
    const unsigned short* __restrict__ Wb, const int* __restrict__ g_idx,
    const float* __restrict__ g_rk, const float* __restrict__ g_rk2,
    float* __restrict__ out)
{
  const int p    = blockIdx.x;
  const int a0   = blockIdx.y * AC;
  const int tid  = threadIdx.x;
  const int wave = tid >> 6;
  const int lane = tid & 63;
  const int quad = lane >> 4;
  const int lq   = lane & 15;

  __shared__ __align__(16) unsigned short s_buf[SBUF_SHORTS];
  __shared__ float s_relx[NN], s_rely[NN], s_relz[NN], s_rel2[NN];
  __shared__ int   s_idx[NN];
  __shared__ float s_rk[AC*KS*3], s_rk2[AC*KS];

  // ---- phase 0: small per-point / per-chunk data ----
  if (tid < NN) {
    const int j = g_idx[p*NN + tid];
    s_idx[tid] = j;
    const float rx = xyz[j]          - xyz[p];
    const float ry = xyz[P_PTS + j]  - xyz[P_PTS + p];
    const float rz = xyz[2*P_PTS + j]- xyz[2*P_PTS + p];
    s_relx[tid] = rx; s_rely[tid] = ry; s_relz[tid] = rz;
    s_rel2[tid] = rx*rx + ry*ry + rz*rz;
  }
  for (int e = tid; e < AC*KS*3; e += 256) s_rk[e]  = g_rk[a0*KS*3 + e];
  for (int e = tid; e < AC*KS;   e += 256) s_rk2[e] = g_rk2[a0*KS + e];
  __syncthreads();

  // ---- phase 1a: gather feats -> gf bf16 LDS [ac][c][n] ----
  #pragma unroll
  for (int pi = 0; pi < 4; ++pi) {
    const int cn = tid + 256*pi;
    const int c = cn >> 5, n = cn & 31;
    const float* src = feats + (size_t)c*(P_PTS*NA) + (size_t)s_idx[n]*NA + a0;
    const float4 v0 = *(const float4*)(src);
    const float4 v1 = *(const float4*)(src + 4);
    const float4 v2 = *(const float4*)(src + 8);
    unsigned short h[12];
    h[0]=f2bf(v0.x); h[1]=f2bf(v0.y); h[2] =f2bf(v0.z); h[3] =f2bf(v0.w);
    h[4]=f2bf(v1.x); h[5]=f2bf(v1.y); h[6] =f2bf(v1.z); h[7] =f2bf(v1.w);
    h[8]=f2bf(v2.x); h[9]=f2bf(v2.y); h[10]=f2bf(v2.z); h[11]=f2bf(v2.w);
    const int base = c*40 + n;
    #pragma unroll
    for (int ac = 0; ac < AC; ++ac) s_buf[ac*1280 + base] = h[ac];
  }

  // ---- phase 1b: interpolation weights w -> bf16 LDS [ac][k][n] ----
  #pragma unroll 4
  for (int i = 0; i < 36; ++i) {           // 12*24*32 / 256
    const int e = tid + (i << 8);
    const int ac = e / (KS*NN);
    const int r  = e - ac*(KS*NN);
    const int k  = r >> 5;
    const int n  = r & 31;
    const int ak = ac*KS + k;
    const float d2 = s_rel2[n] + s_rk2[ak]
        - 2.0f*(s_rk[ak*3+0]*s_relx[n] + s_rk[ak*3+1]*s_rely[n] + s_rk[ak*3+2]*s_relz[n]);
    s_buf[W_OFF(ac, k, n)] = f2bf(fmaxf(0.0f, 1.0f - d2*6.25f));  // relu(1-d2/0.16)
  }
  __syncthreads();

  // ---- phase 2: contraction 1 per anchor: nf[c=32][k=24] = gf[32x32] * w[32n x 24k] ----
  // wave handles anchors wave*3 + {0,1,2}; 2 m-tiles (c) x 2 n-tiles (k, padded)
  f32x4 acc1[3][2][2] = {};
  #pragma unroll
  for (int t = 0; t < 3; ++t) {
    const int a = wave*3 + t;
    const short8 af0 = *(const short8*)&s_buf[GF_OFF(a, lq,      quad*8)];
    const short8 af1 = *(const short8*)&s_buf[GF_OFF(a, 16 + lq, quad*8)];
    const short8 bf0 = *(const short8*)&s_buf[W_OFF(a, lq, quad*8)];
    const int k1 = (lq < 8) ? (16 + lq) : 0;       // clamp in-bounds; cols >=24 discarded
    const short8 bf1 = *(const short8*)&s_buf[W_OFF(a, k1, quad*8)];
    acc1[t][0][0] = __builtin_amdgcn_mfma_f32_16x16x32_bf16(af0, bf0, acc1[t][0][0], 0, 0, 0);
    acc1[t][0][1] = __builtin_amdgcn_mfma_f32_16x16x32_bf16(af0, bf1, acc1[t][0][1], 0, 0, 0);
    acc1[t][1][0] = __builtin_amdgcn_mfma_f32_16x16x32_bf16(af1, bf0, acc1[t][1][0], 0, 0, 0);
    acc1[t][1][1] = __builtin_amdgcn_mfma_f32_16x16x32_bf16(af1, bf1, acc1[t][1][1], 0, 0, 0);
  }
  __syncthreads();   // all gf/w frag reads complete before nf aliases gf region

  // ---- phase 3: nf -> LDS bf16 [ac][ck], ck = c*24 + k ----
  #pragma unroll
  for (int t = 0; t < 3; ++t) {
    const int a = wave*3 + t;
    #pragma unroll
    for (int mt = 0; mt < 2; ++mt) {
      #pragma unroll
      for (int r = 0; r < 4; ++r) {
        const int c = mt*16 + quad*4 + r;
        s_buf[NF_OFF(a, c*KS + lq)] = f2bf(acc1[t][mt][0][r]);
        if (lq < 8)
          s_buf[NF_OFF(a, c*KS + 16 + lq)] = f2bf(acc1[t][mt][1][r]);
      }
    }
  }
  __syncthreads();

  // ---- phase 4: contraction 2: out[o=64][ac=12] = W[64x768] * nf[768 x ac] ----
  // wave owns o-tile [wave*16, wave*16+16); two independent MFMA chains for ILP
  f32x4 accA = {0,0,0,0}, accB = {0,0,0,0};
  const unsigned short* wrow  = Wb + (size_t)(wave*16 + lq)*(CIN*KS) + quad*8;
  const unsigned short* nfrow = &s_buf[NF_OFF(lq, quad*8)];
  #pragma unroll 4
  for (int ks = 0; ks < 24; ks += 2) {
    const short8 aw0 = *(const short8*)(wrow  + ks*32);
    const short8 bn0 = *(const short8*)(nfrow + ks*32);
    const short8 aw1 = *(const short8*)(wrow  + ks*32 + 32);
    const short8 bn1 = *(const short8*)(nfrow + ks*32 + 32);
    accA = __builtin_amdgcn_mfma_f32_16x16x32_bf16(aw0, bn0, accA, 0, 0, 0);
    accB = __builtin_amdgcn_mfma_f32_16x16x32_bf16(aw1, bn1, accB, 0, 0, 0);
  }

  if (lq < AC) {
    const int obase = wave*16 + quad*4;
    #pragma unroll
    for (int r = 0; r < 4; ++r)
      out[(size_t)(obase + r)*(P_PTS*NA) + p*NA + a0 + lq] = accA[r] + accB[r];
  }
}

// ---------------------------------------------------------------------------
extern "C" void kernel_launch(void* const* d_in, const int* in_sizes, int n_in,
                              void* d_out, int out_size, void* d_ws, size_t ws_size,
                              hipStream_t stream) {
  const float* xyz     = (const float*)d_in[0];   // [1,3,1024]
  const float* feats   = (const float*)d_in[1];   // [1,32,1024,60]
  const float* Wm      = (const float*)d_in[2];   // [64,768]
  const float* anchors = (const float*)d_in[3];   // [60,3,3]
  const float* kernels = (const float*)d_in[4];   // [24,3]
  float* out = (float*)d_out;

  // workspace: wbf (98304 B) | idx (131072 B) | rk (3456 B) | rk2 (1152 B)  ~229 KB
  unsigned short* ws_wbf = (unsigned short*)d_ws;
  int*   ws_idx = (int*)((char*)d_ws + 98304);
  float* ws_rk  = (float*)((char*)d_ws + 98304 + 131072);
  float* ws_rk2 = ws_rk + NA*KS*3;

  hipLaunchKernelGGL(ball_query_kernel, dim3(P_PTS/4), dim3(256), 0, stream,
                     xyz, ws_idx);
  hipLaunchKernelGGL(prep_kernel, dim3((COUT*CIN*KS + NA*KS + 255)/256), dim3(256), 0, stream,
                     Wm, anchors, kernels, ws_wbf, ws_rk, ws_rk2);
  hipLaunchKernelGGL(conv_mfma, dim3(P_PTS, NCH), dim3(256), 0, stream,
                     xyz, feats, ws_wbf, ws_idx, ws_rk, ws_rk2, out);
}

// Round 3
// 189.166 us; speedup vs baseline: 1.7345x; 1.0402x over previous
//
#include <hip/hip_runtime.h>

typedef __attribute__((ext_vector_type(8))) short short8;
typedef __attribute__((ext_vector_type(4))) float f32x4;
typedef __attribute__((ext_vector_type(4))) unsigned int uint4v;

#define P_PTS   1024
#define NN      32
#define NA      60
#define KS      24
#define CIN     32
#define COUT    64
#define AC      12          // anchors per chunk
#define NCH     5           // 60 / 12
#define SA      968         // nf LDS anchor stride (shorts): 24*40 + 8 pad

union frag_u { uint4v u; short8 s; };

// full RNE float->bf16 (prep only)
__device__ __forceinline__ unsigned short f2bf(float f) {
  unsigned int u = __float_as_uint(f);
  u += 0x7FFFu + ((u >> 16) & 1u);
  return (unsigned short)(u >> 16);
}
// fast pack: two floats -> bf16x2 (round-half-up), 3 VALU for 2 values
__device__ __forceinline__ unsigned int bfpair(float a, float b) {
  unsigned int ua = __float_as_uint(a) + 0x8000u;
  unsigned int ub = __float_as_uint(b) + 0x8000u;
  return __builtin_amdgcn_perm(ub, ua, 0x07060302u);  // {hi16(b), hi16(a)}
}

// ---------------------------------------------------------------------------
// Ball query: one wave per query point; ordered ballot selection of first NN
// indices (ascending) with d2 < 1, padded with first valid.
// ---------------------------------------------------------------------------
__global__ __launch_bounds__(256) void ball_query_kernel(
    const float* __restrict__ xyz, int* __restrict__ ws_idx)
{
  __shared__ float sx[P_PTS], sy[P_PTS], sz[P_PTS], sq[P_PTS];
  __shared__ int s_loc[4][NN];
  const int tid = threadIdx.x;

  for (int i = tid; i < P_PTS; i += 256) {
    float x = xyz[i], y = xyz[P_PTS + i], z = xyz[2*P_PTS + i];
    sx[i] = x; sy[i] = y; sz[i] = z;
    sq[i] = x*x + y*y + z*z;
  }
  __syncthreads();

  const int wave = tid >> 6;
  const int lane = tid & 63;
  const int q = blockIdx.x * 4 + wave;

  const float xq = sx[q], yq = sy[q], zq = sz[q], sqq = sq[q];
  int cnt = 0;
  for (int jb = 0; jb < P_PTS; jb += 64) {
    const int j = jb + lane;
    const float d2 = sqq + sq[j] - 2.0f*(xq*sx[j] + yq*sy[j] + zq*sz[j]);
    const bool pred = d2 < 1.0f;
    const unsigned long long mask = __ballot(pred);
    if (pred) {
      const int slot = cnt + __popcll(mask & ((1ull << lane) - 1ull));
      if (slot < NN) s_loc[wave][slot] = j;
    }
    cnt += (int)__popcll(mask);
    if (cnt >= NN) break;
  }
  __syncthreads();
  const int cntc = cnt < NN ? cnt : NN;
  if (lane >= cntc && lane < NN) s_loc[wave][lane] = s_loc[wave][0];
  __syncthreads();
  if (lane < NN) ws_idx[q*NN + lane] = s_loc[wave][lane];
}

// ---------------------------------------------------------------------------
// Prep: W -> bf16 permuted to [o][k][c] (ck' = k*32+c); rotated kernel points
// pre-scaled: rk4 = (12.5*rk, 1 - 6.25*|rk|^2) so w = fma-chain with rel4.
// ---------------------------------------------------------------------------
__global__ __launch_bounds__(256) void prep_kernel(
    const float* __restrict__ Wm, const float* __restrict__ anchors,
    const float* __restrict__ kernels, unsigned short* __restrict__ wbf,
    float4* __restrict__ rk4)
{
  const int t = blockIdx.x * 256 + threadIdx.x;
  if (t < COUT*CIN*KS) {
    const int o = t / (CIN*KS), r = t - o*(CIN*KS);
    const int k = r >> 5, c = r & 31;
    wbf[t] = f2bf(Wm[o*(CIN*KS) + c*KS + k]);
  }
  const int u = t - COUT*CIN*KS;
  if (u >= 0 && u < NA*KS) {
    const int a = u / KS, k = u - a*KS;
    const float rx = anchors[a*9+0]*kernels[k*3+0] + anchors[a*9+1]*kernels[k*3+1] + anchors[a*9+2]*kernels[k*3+2];
    const float ry = anchors[a*9+3]*kernels[k*3+0] + anchors[a*9+4]*kernels[k*3+1] + anchors[a*9+5]*kernels[k*3+2];
    const float rz = anchors[a*9+6]*kernels[k*3+0] + anchors[a*9+7]*kernels[k*3+1] + anchors[a*9+8]*kernels[k*3+2];
    rk4[u] = make_float4(12.5f*rx, 12.5f*ry, 12.5f*rz,
                         1.0f - 6.25f*(rx*rx + ry*ry + rz*rz));
  }
}

// w = relu(1 - d2/0.16) = max(0, (1-6.25|rk|^2) - 6.25|rel|^2 + 12.5<rk,rel>)
__device__ __forceinline__ float wcalc(const float4 rk, const float4 rl) {
  return fmaxf(0.0f, fmaf(rk.x, rl.x, fmaf(rk.y, rl.y, fmaf(rk.z, rl.z, rk.w + rl.w))));
}

// ---------------------------------------------------------------------------
// Main fused kernel. Block = (point p, chunk of 12 anchors). No LDS staging
// of gf/w: A-frags gathered direct from global, w computed in registers.
// LDS only holds nf (contraction-1 output, layout [a][k*40+c]) + small data.
// ---------------------------------------------------------------------------
__global__ __launch_bounds__(256, 4) void conv_mfma(
    const float* __restrict__ xyz, const float* __restrict__ feats,
    const unsigned short* __restrict__ Wb, const int* __restrict__ g_idx,
    const float4* __restrict__ g_rk4, float* __restrict__ out)
{
  const int p    = blockIdx.x;
  const int a0   = blockIdx.y * AC;
  const int tid  = threadIdx.x;
  const int wave = tid >> 6;
  const int lane = tid & 63;
  const int quad = lane >> 4;
  const int lq   = lane & 15;

  __shared__ __align__(16) unsigned short s_nf[AC*SA];   // 23232 B
  __shared__ __align__(16) float4 s_rel4[NN];            // (rx,ry,rz,-6.25*|r|^2)
  __shared__ __align__(16) float4 s_rk4[AC*KS];
  __shared__ int s_idx[NN];

  // ---- phase 0 ----
  if (tid < NN) {
    const int j = g_idx[p*NN + tid];
    s_idx[tid] = j;
    const float rx = xyz[j]           - xyz[p];
    const float ry = xyz[P_PTS + j]   - xyz[P_PTS + p];
    const float rz = xyz[2*P_PTS + j] - xyz[2*P_PTS + p];
    s_rel4[tid] = make_float4(rx, ry, rz, -6.25f*(rx*rx + ry*ry + rz*rz));
  }
  for (int e = tid; e < AC*KS; e += 256) s_rk4[e] = g_rk4[a0*KS + e];
  __syncthreads();

  // ---- contraction 1: per wave, anchors wave*3 + {0,1,2} ----
  const int nbase = quad * 8;
  int idx8[8];
  #pragma unroll
  for (int j = 0; j < 8; ++j) idx8[j] = s_idx[nbase + j];

  // A gather: float3 covers the wave's 3 anchors for (c, n)
  float ga[2][8][3];
  #pragma unroll
  for (int mt = 0; mt < 2; ++mt)
    #pragma unroll
    for (int j = 0; j < 8; ++j) {
      const float3 v = *(const float3*)(feats + (mt*16 + lq)*(P_PTS*NA)
                                        + idx8[j]*NA + (a0 + wave*3));
      ga[mt][j][0] = v.x; ga[mt][j][1] = v.y; ga[mt][j][2] = v.z;
    }

  float4 rel[8];
  #pragma unroll
  for (int j = 0; j < 8; ++j) rel[j] = s_rel4[nbase + j];

  // pack A-frags, then ga dies
  frag_u af[3][2];
  #pragma unroll
  for (int t = 0; t < 3; ++t)
    #pragma unroll
    for (int mt = 0; mt < 2; ++mt)
      #pragma unroll
      for (int i = 0; i < 4; ++i)
        af[t][mt].u[i] = bfpair(ga[mt][2*i][t], ga[mt][2*i+1][t]);

  #pragma unroll
  for (int t = 0; t < 3; ++t) {
    const int a  = wave*3 + t;
    const int k1 = (lq < 8) ? (16 + lq) : 23;     // clamped; cols>=24 discarded
    const float4 rk0 = s_rk4[a*KS + lq];
    const float4 rk1 = s_rk4[a*KS + k1];
    frag_u b0, b1;
    #pragma unroll
    for (int i = 0; i < 4; ++i) {
      const float w00 = wcalc(rk0, rel[2*i]);
      const float w01 = wcalc(rk0, rel[2*i+1]);
      const float w10 = wcalc(rk1, rel[2*i]);
      const float w11 = wcalc(rk1, rel[2*i+1]);
      b0.u[i] = bfpair(w00, w01);
      b1.u[i] = bfpair(w10, w11);
    }
    f32x4 z = {0.f, 0.f, 0.f, 0.f};
    f32x4 d00 = __builtin_amdgcn_mfma_f32_16x16x32_bf16(af[t][0].s, b0.s, z, 0, 0, 0);
    f32x4 d10 = __builtin_amdgcn_mfma_f32_16x16x32_bf16(af[t][1].s, b0.s, z, 0, 0, 0);
    f32x4 d01 = __builtin_amdgcn_mfma_f32_16x16x32_bf16(af[t][0].s, b1.s, z, 0, 0, 0);
    f32x4 d11 = __builtin_amdgcn_mfma_f32_16x16x32_bf16(af[t][1].s, b1.s, z, 0, 0, 0);

    // nf[a][k*40 + c] writes, packed b64 (4 consecutive c per lane)
    unsigned short* row = &s_nf[a*SA];
    uint2 pk;
    pk.x = bfpair(d00[0], d00[1]); pk.y = bfpair(d00[2], d00[3]);
    *(uint2*)&row[lq*40 + quad*4] = pk;
    pk.x = bfpair(d10[0], d10[1]); pk.y = bfpair(d10[2], d10[3]);
    *(uint2*)&row[lq*40 + 16 + quad*4] = pk;
    if (lq < 8) {
      pk.x = bfpair(d01[0], d01[1]); pk.y = bfpair(d01[2], d01[3]);
      *(uint2*)&row[(16+lq)*40 + quad*4] = pk;
      pk.x = bfpair(d11[0], d11[1]); pk.y = bfpair(d11[2], d11[3]);
      *(uint2*)&row[(16+lq)*40 + 16 + quad*4] = pk;
    }
  }
  __syncthreads();

  // ---- contraction 2: out[o=64][ac=12] = Wb[64 x 768] * nf[768 x ac] ----
  const int acl = (lq < AC) ? lq : (AC - 1);      // clamp; cols 12..15 discarded
  const unsigned short* wptr = Wb + (size_t)(wave*16 + lq)*(CIN*KS) + quad*8;
  const unsigned short* nptr = &s_nf[acl*SA + quad*8];
  f32x4 accA = {0.f,0.f,0.f,0.f}, accB = {0.f,0.f,0.f,0.f};
  #pragma unroll 4
  for (int s = 0; s < 24; s += 2) {
    const short8 aw0 = *(const short8*)(wptr + s*32);
    const short8 bn0 = *(const short8*)(nptr + s*40);
    const short8 aw1 = *(const short8*)(wptr + s*32 + 32);
    const short8 bn1 = *(const short8*)(nptr + s*40 + 40);
    accA = __builtin_amdgcn_mfma_f32_16x16x32_bf16(aw0, bn0, accA, 0, 0, 0);
    accB = __builtin_amdgcn_mfma_f32_16x16x32_bf16(aw1, bn1, accB, 0, 0, 0);
  }

  if (lq < AC) {
    const int ob = wave*16 + quad*4;
    #pragma unroll
    for (int r = 0; r < 4; ++r)
      out[(size_t)(ob + r)*(P_PTS*NA) + p*NA + a0 + lq] = accA[r] + accB[r];
  }
}

// ---------------------------------------------------------------------------
extern "C" void kernel_launch(void* const* d_in, const int* in_sizes, int n_in,
                              void* d_out, int out_size, void* d_ws, size_t ws_size,
                              hipStream_t stream) {
  const float* xyz     = (const float*)d_in[0];   // [1,3,1024]
  const float* feats   = (const float*)d_in[1];   // [1,32,1024,60]
  const float* Wm      = (const float*)d_in[2];   // [64,768]
  const float* anchors = (const float*)d_in[3];   // [60,3,3]
  const float* kernels = (const float*)d_in[4];   // [24,3]
  float* out = (float*)d_out;

  // ws: Wb permuted bf16 (98304 B) | idx (131072 B) | rk4 (23040 B)
  unsigned short* ws_wbf = (unsigned short*)d_ws;
  int*    ws_idx = (int*)((char*)d_ws + 98304);
  float4* ws_rk4 = (float4*)((char*)d_ws + 98304 + 131072);

  hipLaunchKernelGGL(ball_query_kernel, dim3(P_PTS/4), dim3(256), 0, stream,
                     xyz, ws_idx);
  hipLaunchKernelGGL(prep_kernel, dim3((COUT*CIN*KS + NA*KS + 255)/256), dim3(256), 0, stream,
                     Wm, anchors, kernels, ws_wbf, ws_rk4);
  hipLaunchKernelGGL(conv_mfma, dim3(P_PTS, NCH), dim3(256), 0, stream,
                     xyz, feats, ws_wbf, ws_idx, ws_rk4, out);
}

// Round 4
// 147.651 us; speedup vs baseline: 2.2222x; 1.2812x over previous
//
#include <hip/hip_runtime.h>

typedef __attribute__((ext_vector_type(8))) short short8;
typedef __attribute__((ext_vector_type(4))) float f32x4;
typedef __attribute__((ext_vector_type(4))) unsigned int uint4v;

#define P_PTS   1024
#define NN      32
#define NA      60
#define KS      24
#define CIN     32
#define COUT    64
#define AC      12          // anchors per chunk
#define NCH     5           // 60 / 12
#define SA      968         // nf LDS anchor stride (shorts): 24*40 + 8 pad

union frag_u { uint4v u; short8 s; };

// full RNE float->bf16
__device__ __forceinline__ unsigned short f2bf(float f) {
  unsigned int u = __float_as_uint(f);
  u += 0x7FFFu + ((u >> 16) & 1u);
  return (unsigned short)(u >> 16);
}
// fast pack: two floats -> bf16x2 (round-half-up)
__device__ __forceinline__ unsigned int bfpair(float a, float b) {
  unsigned int ua = __float_as_uint(a) + 0x8000u;
  unsigned int ub = __float_as_uint(b) + 0x8000u;
  return __builtin_amdgcn_perm(ub, ua, 0x07060302u);  // {hi16(b), hi16(a)}
}

// ---------------------------------------------------------------------------
// Ball query: one wave per query point; ordered ballot selection of first NN
// indices (ascending) with d2 < 1, padded with first valid.
// ---------------------------------------------------------------------------
__global__ __launch_bounds__(256) void ball_query_kernel(
    const float* __restrict__ xyz, int* __restrict__ ws_idx)
{
  __shared__ float sx[P_PTS], sy[P_PTS], sz[P_PTS], sq[P_PTS];
  __shared__ int s_loc[4][NN];
  const int tid = threadIdx.x;

  for (int i = tid; i < P_PTS; i += 256) {
    float x = xyz[i], y = xyz[P_PTS + i], z = xyz[2*P_PTS + i];
    sx[i] = x; sy[i] = y; sz[i] = z;
    sq[i] = x*x + y*y + z*z;
  }
  __syncthreads();

  const int wave = tid >> 6;
  const int lane = tid & 63;
  const int q = blockIdx.x * 4 + wave;

  const float xq = sx[q], yq = sy[q], zq = sz[q], sqq = sq[q];
  int cnt = 0;
  for (int jb = 0; jb < P_PTS; jb += 64) {
    const int j = jb + lane;
    const float d2 = sqq + sq[j] - 2.0f*(xq*sx[j] + yq*sy[j] + zq*sz[j]);
    const bool pred = d2 < 1.0f;
    const unsigned long long mask = __ballot(pred);
    if (pred) {
      const int slot = cnt + __popcll(mask & ((1ull << lane) - 1ull));
      if (slot < NN) s_loc[wave][slot] = j;
    }
    cnt += (int)__popcll(mask);
    if (cnt >= NN) break;
  }
  __syncthreads();
  const int cntc = cnt < NN ? cnt : NN;
  if (lane >= cntc && lane < NN) s_loc[wave][lane] = s_loc[wave][0];
  __syncthreads();
  if (lane < NN) ws_idx[q*NN + lane] = s_loc[wave][lane];
}

// ---------------------------------------------------------------------------
// Transpose feats [c][p][a] fp32 -> ft [p][a][c] bf16 (c-contiguous rows:
// one (p,a) row = 64 B = exactly one cacheline).
// ---------------------------------------------------------------------------
__global__ __launch_bounds__(256) void transpose_kernel(
    const float* __restrict__ feats, unsigned short* __restrict__ ft)
{
  const int p = blockIdx.x;
  __shared__ unsigned short s_t[CIN*NA];   // [c][a]
  const int tid = threadIdx.x;
  for (int e = tid; e < CIN*NA; e += 256) {
    const int c = e / NA, a = e - c*NA;
    s_t[e] = f2bf(feats[c*(P_PTS*NA) + p*NA + a]);
  }
  __syncthreads();
  unsigned int* out32 = (unsigned int*)(ft + p*(CIN*NA));
  for (int e = tid; e < (CIN*NA)/2; e += 256) {
    const int a = e >> 4, cu = e & 15;
    const unsigned int lo = s_t[(2*cu    )*NA + a];
    const unsigned int hi = s_t[(2*cu + 1)*NA + a];
    out32[a*16 + cu] = lo | (hi << 16);
  }
}

// ---------------------------------------------------------------------------
// Prep: W -> bf16 permuted to [o][k][c] (ck' = k*32+c); rotated kernel points
// pre-scaled: rk4 = (12.5*rk, 1 - 6.25*|rk|^2).
// ---------------------------------------------------------------------------
__global__ __launch_bounds__(256) void prep_kernel(
    const float* __restrict__ Wm, const float* __restrict__ anchors,
    const float* __restrict__ kernels, unsigned short* __restrict__ wbf,
    float4* __restrict__ rk4)
{
  const int t = blockIdx.x * 256 + threadIdx.x;
  if (t < COUT*CIN*KS) {
    const int o = t / (CIN*KS), r = t - o*(CIN*KS);
    const int k = r >> 5, c = r & 31;
    wbf[t] = f2bf(Wm[o*(CIN*KS) + c*KS + k]);
  }
  const int u = t - COUT*CIN*KS;
  if (u >= 0 && u < NA*KS) {
    const int a = u / KS, k = u - a*KS;
    const float rx = anchors[a*9+0]*kernels[k*3+0] + anchors[a*9+1]*kernels[k*3+1] + anchors[a*9+2]*kernels[k*3+2];
    const float ry = anchors[a*9+3]*kernels[k*3+0] + anchors[a*9+4]*kernels[k*3+1] + anchors[a*9+5]*kernels[k*3+2];
    const float rz = anchors[a*9+6]*kernels[k*3+0] + anchors[a*9+7]*kernels[k*3+1] + anchors[a*9+8]*kernels[k*3+2];
    rk4[u] = make_float4(12.5f*rx, 12.5f*ry, 12.5f*rz,
                         1.0f - 6.25f*(rx*rx + ry*ry + rz*rz));
  }
}

// w = relu(1 - d2/0.16) = max(0, (1-6.25|rk|^2) - 6.25|rel|^2 + 12.5<rk,rel>)
__device__ __forceinline__ float wcalc(const float4 rk, const float4 rl) {
  return fmaxf(0.0f, fmaf(rk.x, rl.x, fmaf(rk.y, rl.y, fmaf(rk.z, rl.z, rk.w + rl.w))));
}

// ---------------------------------------------------------------------------
// Main fused kernel. Block = (point p, chunk of 12 anchors).
// gf staged coalesced from ft (1 line per (n,a) row); w in registers;
// nf LDS aliases the gf region after a barrier.
// ---------------------------------------------------------------------------
__global__ __launch_bounds__(256, 4) void conv_mfma(
    const float* __restrict__ xyz, const unsigned short* __restrict__ ft,
    const unsigned short* __restrict__ Wb, const int* __restrict__ g_idx,
    const float4* __restrict__ g_rk4, float* __restrict__ out)
{
  const int p    = blockIdx.x;
  const int a0   = blockIdx.y * AC;
  const int tid  = threadIdx.x;
  const int wave = tid >> 6;
  const int lane = tid & 63;
  const int quad = lane >> 4;
  const int lq   = lane & 15;

  // gf[a][n][c]: a*1024 + n*32 + c (shorts); later aliased by nf[a][k*40+c]
  __shared__ __align__(16) unsigned short s_buf[AC*NN*CIN];  // 24576 B
  __shared__ __align__(16) float4 s_rel4[NN];   // (rx,ry,rz,-6.25*|r|^2)
  __shared__ __align__(16) float4 s_rk4[AC*KS];
  __shared__ int s_idx[NN];

  // ---- phase 0 ----
  if (tid < NN) {
    const int j = g_idx[p*NN + tid];
    s_idx[tid] = j;
    const float rx = xyz[j]           - xyz[p];
    const float ry = xyz[P_PTS + j]   - xyz[P_PTS + p];
    const float rz = xyz[2*P_PTS + j] - xyz[2*P_PTS + p];
    s_rel4[tid] = make_float4(rx, ry, rz, -6.25f*(rx*rx + ry*ry + rz*rz));
  }
  for (int e = tid; e < AC*KS; e += 256) s_rk4[e] = g_rk4[a0*KS + e];
  __syncthreads();

  // ---- phase 1: stage gf, wave-coalesced (16 cachelines / instruction) ----
  #pragma unroll
  for (int i = 0; i < 6; ++i) {
    const int e  = tid + (i << 8);        // 0..1535 chunks of 16 B
    const int a  = e >> 7;
    const int r  = e & 127;
    const int n  = r >> 2;
    const int ce = r & 3;
    const uint4 v = *(const uint4*)(ft + s_idx[n]*(CIN*NA) + (a0 + a)*CIN + ce*8);
    *(uint4*)(&s_buf[a*1024 + n*32 + ce*8]) = v;
  }
  __syncthreads();

  // ---- contraction 1: per wave, anchors wave*3 + {0,1,2} ----
  f32x4 acc1[3][2][2] = {};
  #pragma unroll
  for (int t = 0; t < 3; ++t) {
    const int a = wave*3 + t;
    // A-frags from LDS: A[m = mt*16+lq][kd = n = quad*8+j]
    frag_u af0, af1;
    #pragma unroll
    for (int i = 0; i < 4; ++i) {
      const int base = a*1024 + (quad*8 + 2*i)*32;
      const unsigned int x0 = s_buf[base      + lq];
      const unsigned int y0 = s_buf[base + 32 + lq];
      const unsigned int x1 = s_buf[base      + 16 + lq];
      const unsigned int y1 = s_buf[base + 32 + 16 + lq];
      af0.u[i] = x0 | (y0 << 16);
      af1.u[i] = x1 | (y1 << 16);
    }
    // B-frags: w computed in registers. B[kd = n][col = k]
    const int k1 = (lq < 8) ? (16 + lq) : 23;     // clamped; cols>=24 discarded
    const float4 rk0 = s_rk4[a*KS + lq];
    const float4 rk1 = s_rk4[a*KS + k1];
    frag_u b0, b1;
    #pragma unroll
    for (int i = 0; i < 4; ++i) {
      const float4 rA = s_rel4[quad*8 + 2*i];
      const float4 rB = s_rel4[quad*8 + 2*i + 1];
      b0.u[i] = bfpair(wcalc(rk0, rA), wcalc(rk0, rB));
      b1.u[i] = bfpair(wcalc(rk1, rA), wcalc(rk1, rB));
    }
    acc1[t][0][0] = __builtin_amdgcn_mfma_f32_16x16x32_bf16(af0.s, b0.s, acc1[t][0][0], 0, 0, 0);
    acc1[t][0][1] = __builtin_amdgcn_mfma_f32_16x16x32_bf16(af0.s, b1.s, acc1[t][0][1], 0, 0, 0);
    acc1[t][1][0] = __builtin_amdgcn_mfma_f32_16x16x32_bf16(af1.s, b0.s, acc1[t][1][0], 0, 0, 0);
    acc1[t][1][1] = __builtin_amdgcn_mfma_f32_16x16x32_bf16(af1.s, b1.s, acc1[t][1][1], 0, 0, 0);
  }
  __syncthreads();   // all gf reads complete before nf aliases the region

  // ---- phase 3: nf -> LDS bf16 [a][k*40 + c] ----
  #pragma unroll
  for (int t = 0; t < 3; ++t) {
    const int a = wave*3 + t;
    unsigned short* row = &s_buf[a*SA];
    uint2 pk;
    pk.x = bfpair(acc1[t][0][0][0], acc1[t][0][0][1]);
    pk.y = bfpair(acc1[t][0][0][2], acc1[t][0][0][3]);
    *(uint2*)&row[lq*40 + quad*4] = pk;                    // mt0, k=lq
    pk.x = bfpair(acc1[t][1][0][0], acc1[t][1][0][1]);
    pk.y = bfpair(acc1[t][1][0][2], acc1[t][1][0][3]);
    *(uint2*)&row[lq*40 + 16 + quad*4] = pk;               // mt1, k=lq
    if (lq < 8) {
      pk.x = bfpair(acc1[t][0][1][0], acc1[t][0][1][1]);
      pk.y = bfpair(acc1[t][0][1][2], acc1[t][0][1][3]);
      *(uint2*)&row[(16+lq)*40 + quad*4] = pk;             // mt0, k=16+lq
      pk.x = bfpair(acc1[t][1][1][0], acc1[t][1][1][1]);
      pk.y = bfpair(acc1[t][1][1][2], acc1[t][1][1][3]);
      *(uint2*)&row[(16+lq)*40 + 16 + quad*4] = pk;        // mt1, k=16+lq
    }
  }
  __syncthreads();

  // ---- contraction 2: out[o=64][ac=12] = Wb[64 x 768] * nf[768 x ac] ----
  const int acl = (lq < AC) ? lq : (AC - 1);      // clamp; cols 12..15 discarded
  const unsigned short* wptr = Wb + (size_t)(wave*16 + lq)*(CIN*KS) + quad*8;
  const unsigned short* nptr = &s_buf[acl*SA + quad*8];
  f32x4 accA = {0.f,0.f,0.f,0.f}, accB = {0.f,0.f,0.f,0.f};
  #pragma unroll 4
  for (int s = 0; s < 24; s += 2) {
    const short8 aw0 = *(const short8*)(wptr + s*32);
    const short8 bn0 = *(const short8*)(nptr + s*40);
    const short8 aw1 = *(const short8*)(wptr + s*32 + 32);
    const short8 bn1 = *(const short8*)(nptr + s*40 + 40);
    accA = __builtin_amdgcn_mfma_f32_16x16x32_bf16(aw0, bn0, accA, 0, 0, 0);
    accB = __builtin_amdgcn_mfma_f32_16x16x32_bf16(aw1, bn1, accB, 0, 0, 0);
  }

  if (lq < AC) {
    const int ob = wave*16 + quad*4;
    #pragma unroll
    for (int r = 0; r < 4; ++r)
      out[(size_t)(ob + r)*(P_PTS*NA) + p*NA + a0 + lq] = accA[r] + accB[r];
  }
}

// ---------------------------------------------------------------------------
extern "C" void kernel_launch(void* const* d_in, const int* in_sizes, int n_in,
                              void* d_out, int out_size, void* d_ws, size_t ws_size,
                              hipStream_t stream) {
  const float* xyz     = (const float*)d_in[0];   // [1,3,1024]
  const float* feats   = (const float*)d_in[1];   // [1,32,1024,60]
  const float* Wm      = (const float*)d_in[2];   // [64,768]
  const float* anchors = (const float*)d_in[3];   // [60,3,3]
  const float* kernels = (const float*)d_in[4];   // [24,3]
  float* out = (float*)d_out;

  // ws: Wb bf16 (98304 B) | idx (131072 B) | rk4 (23040 B) | ft bf16 (3932160 B)
  unsigned short* ws_wbf = (unsigned short*)d_ws;
  int*    ws_idx = (int*)((char*)d_ws + 98304);
  float4* ws_rk4 = (float4*)((char*)d_ws + 98304 + 131072);
  unsigned short* ws_ft = (unsigned short*)((char*)d_ws + 98304 + 131072 + 23040);

  hipLaunchKernelGGL(ball_query_kernel, dim3(P_PTS/4), dim3(256), 0, stream,
                     xyz, ws_idx);
  hipLaunchKernelGGL(transpose_kernel, dim3(P_PTS), dim3(256), 0, stream,
                     feats, ws_ft);
  hipLaunchKernelGGL(prep_kernel, dim3((COUT*CIN*KS + NA*KS + 255)/256), dim3(256), 0, stream,
                     Wm, anchors, kernels, ws_wbf, ws_rk4);
  hipLaunchKernelGGL(conv_mfma, dim3(P_PTS, NCH), dim3(256), 0, stream,
                     xyz, ws_ft, ws_wbf, ws_idx, ws_rk4, out);
}

// Round 6
// 145.538 us; speedup vs baseline: 2.2545x; 1.0145x over previous
//
#include <hip/hip_runtime.h>

typedef __attribute__((ext_vector_type(8))) short short8;
typedef __attribute__((ext_vector_type(4))) float f32x4;
typedef __attribute__((ext_vector_type(4))) unsigned int uint4v;

#define P_PTS   1024
#define NN      32
#define NA      60
#define KS      24
#define CIN     32
#define COUT    64
#define AC      12          // anchors per chunk
#define NCH     5           // 60 / 12
#define SA      968         // nf LDS anchor stride (shorts): 24*40 + 8 pad
// gf interleaved layout: short addr = a*1088 + n2*68 + c*2 + parity
//   (dword addr = a*544 + n2*34 + c ; dword = {bf16(n=2*n2), bf16(n=2*n2+1)})
#define GF_SHORTS (AC*16*68)   // 13056 shorts = 26112 B  (>= nf 11616 shorts)

union frag_u { uint4v u; short8 s; };

// full RNE float->bf16
__device__ __forceinline__ unsigned short f2bf(float f) {
  unsigned int u = __float_as_uint(f);
  u += 0x7FFFu + ((u >> 16) & 1u);
  return (unsigned short)(u >> 16);
}
// fast pack: two floats -> bf16x2 (round-half-up)
__device__ __forceinline__ unsigned int bfpair(float a, float b) {
  unsigned int ua = __float_as_uint(a) + 0x8000u;
  unsigned int ub = __float_as_uint(b) + 0x8000u;
  return __builtin_amdgcn_perm(ub, ua, 0x07060302u);  // {hi16(b), hi16(a)}
}
// interleave low/high shorts of two dwords: lo = {u.s0, v.s0}, hi = {u.s1, v.s1}
__device__ __forceinline__ void ilv(unsigned int u, unsigned int v,
                                    unsigned int& lo, unsigned int& hi) {
  lo = __builtin_amdgcn_perm(v, u, 0x05040100u);
  hi = __builtin_amdgcn_perm(v, u, 0x07060302u);
}

// w = relu(1 - d2/0.16) = max(0, (1-6.25|rk|^2) - 6.25|rel|^2 + 12.5<rk,rel>)
__device__ __forceinline__ float wcalc(const float4 rk, const float4 rl) {
  return fmaxf(0.0f, fmaf(rk.x, rl.x, fmaf(rk.y, rl.y, fmaf(rk.z, rl.z, rk.w + rl.w))));
}

// ---------------------------------------------------------------------------
// Ball query: one wave per query point; ordered ballot selection of first NN
// indices (ascending) with d2 < 1, padded with first valid.
// ---------------------------------------------------------------------------
__global__ __launch_bounds__(256) void ball_query_kernel(
    const float* __restrict__ xyz, int* __restrict__ ws_idx)
{
  __shared__ float sx[P_PTS], sy[P_PTS], sz[P_PTS], sq[P_PTS];
  __shared__ int s_loc[4][NN];
  const int tid = threadIdx.x;

  for (int i = tid; i < P_PTS; i += 256) {
    float x = xyz[i], y = xyz[P_PTS + i], z = xyz[2*P_PTS + i];
    sx[i] = x; sy[i] = y; sz[i] = z;
    sq[i] = x*x + y*y + z*z;
  }
  __syncthreads();

  const int wave = tid >> 6;
  const int lane = tid & 63;
  const int q = blockIdx.x * 4 + wave;

  const float xq = sx[q], yq = sy[q], zq = sz[q], sqq = sq[q];
  int cnt = 0;
  for (int jb = 0; jb < P_PTS; jb += 64) {
    const int j = jb + lane;
    const float d2 = sqq + sq[j] - 2.0f*(xq*sx[j] + yq*sy[j] + zq*sz[j]);
    const bool pred = d2 < 1.0f;
    const unsigned long long mask = __ballot(pred);
    if (pred) {
      const int slot = cnt + __popcll(mask & ((1ull << lane) - 1ull));
      if (slot < NN) s_loc[wave][slot] = j;
    }
    cnt += (int)__popcll(mask);
    if (cnt >= NN) break;
  }
  __syncthreads();
  const int cntc = cnt < NN ? cnt : NN;
  if (lane >= cntc && lane < NN) s_loc[wave][lane] = s_loc[wave][0];
  __syncthreads();
  if (lane < NN) ws_idx[q*NN + lane] = s_loc[wave][lane];
}

// ---------------------------------------------------------------------------
// Transpose feats [c][p][a] fp32 -> ft [p][a][c] bf16 (c-contiguous rows:
// one (p,a) row = 64 B = exactly one cacheline).
// ---------------------------------------------------------------------------
__global__ __launch_bounds__(256) void transpose_kernel(
    const float* __restrict__ feats, unsigned short* __restrict__ ft)
{
  const int p = blockIdx.x;
  __shared__ unsigned short s_t[CIN*NA];   // [c][a]
  const int tid = threadIdx.x;
  for (int e = tid; e < CIN*NA; e += 256) {
    const int c = e / NA, a = e - c*NA;
    s_t[e] = f2bf(feats[c*(P_PTS*NA) + p*NA + a]);
  }
  __syncthreads();
  unsigned int* out32 = (unsigned int*)(ft + p*(CIN*NA));
  for (int e = tid; e < (CIN*NA)/2; e += 256) {
    const int a = e >> 4, cu = e & 15;
    const unsigned int lo = s_t[(2*cu    )*NA + a];
    const unsigned int hi = s_t[(2*cu + 1)*NA + a];
    out32[a*16 + cu] = lo | (hi << 16);
  }
}

// ---------------------------------------------------------------------------
// Prep: W -> bf16 permuted to [o][k][c] (ck' = k*32+c); rotated kernel points
// pre-scaled: rk4 = (12.5*rk, 1 - 6.25*|rk|^2).
// ---------------------------------------------------------------------------
__global__ __launch_bounds__(256) void prep_kernel(
    const float* __restrict__ Wm, const float* __restrict__ anchors,
    const float* __restrict__ kernels, unsigned short* __restrict__ wbf,
    float4* __restrict__ rk4)
{
  const int t = blockIdx.x * 256 + threadIdx.x;
  if (t < COUT*CIN*KS) {
    const int o = t / (CIN*KS), r = t - o*(CIN*KS);
    const int k = r >> 5, c = r & 31;
    wbf[t] = f2bf(Wm[o*(CIN*KS) + c*KS + k]);
  }
  const int u = t - COUT*CIN*KS;
  if (u >= 0 && u < NA*KS) {
    const int a = u / KS, k = u - a*KS;
    const float rx = anchors[a*9+0]*kernels[k*3+0] + anchors[a*9+1]*kernels[k*3+1] + anchors[a*9+2]*kernels[k*3+2];
    const float ry = anchors[a*9+3]*kernels[k*3+0] + anchors[a*9+4]*kernels[k*3+1] + anchors[a*9+5]*kernels[k*3+2];
    const float rz = anchors[a*9+6]*kernels[k*3+0] + anchors[a*9+7]*kernels[k*3+1] + anchors[a*9+8]*kernels[k*3+2];
    rk4[u] = make_float4(12.5f*rx, 12.5f*ry, 12.5f*rz,
                         1.0f - 6.25f*(rx*rx + ry*ry + rz*rz));
  }
}

// ---------------------------------------------------------------------------
// Main fused kernel. Block = (point p, chunk of 12 anchors).
// gf staged coalesced from ft with neighbor-pair interleaving so A-frags are
// single ds_read_b32, 2-way bank aliasing (free). w in registers; nf aliases
// gf region after a barrier.
// ---------------------------------------------------------------------------
__global__ __launch_bounds__(256, 4) void conv_mfma(
    const float* __restrict__ xyz, const unsigned short* __restrict__ ft,
    const unsigned short* __restrict__ Wb, const int* __restrict__ g_idx,
    const float4* __restrict__ g_rk4, float* __restrict__ out)
{
  const int p    = blockIdx.x;
  const int a0   = blockIdx.y * AC;
  const int tid  = threadIdx.x;
  const int wave = tid >> 6;
  const int lane = tid & 63;
  const int quad = lane >> 4;
  const int lq   = lane & 15;

  __shared__ __align__(16) unsigned short s_buf[GF_SHORTS];  // 26112 B, aliased by nf
  __shared__ __align__(16) float4 s_rel4[NN];   // (rx,ry,rz,-6.25*|r|^2)
  __shared__ __align__(16) float4 s_rk4[AC*KS];
  __shared__ int s_idx[NN];

  // ---- phase 0 ----
  if (tid < NN) {
    const int j = g_idx[p*NN + tid];
    s_idx[tid] = j;
    const float rx = xyz[j]           - xyz[p];
    const float ry = xyz[P_PTS + j]   - xyz[P_PTS + p];
    const float rz = xyz[2*P_PTS + j] - xyz[2*P_PTS + p];
    s_rel4[tid] = make_float4(rx, ry, rz, -6.25f*(rx*rx + ry*ry + rz*rz));
  }
  for (int e = tid; e < AC*KS; e += 256) s_rk4[e] = g_rk4[a0*KS + e];
  __syncthreads();

  // ---- staging: thread owns (n-pair np, c-chunk ce), 3 anchors ----
  const int np = (tid >> 2) & 15;
  const int ce = tid & 3;
  const int i0 = s_idx[2*np];
  const int i1 = s_idx[2*np + 1];
  const unsigned short* ft0 = ft + (size_t)i0*(CIN*NA) + a0*CIN + ce*8;
  const unsigned short* ft1 = ft + (size_t)i1*(CIN*NA) + a0*CIN + ce*8;
  #pragma unroll
  for (int i = 0; i < 3; ++i) {
    const int a = i*4 + wave;
    const uint4 u = *(const uint4*)(ft0 + a*CIN);
    const uint4 v = *(const uint4*)(ft1 + a*CIN);
    unsigned short* dst = &s_buf[a*1088 + np*68 + ce*16];
    unsigned int d0, d1;
    ilv(u.x, v.x, d0, d1); *(uint2*)(dst +  0) = make_uint2(d0, d1);
    ilv(u.y, v.y, d0, d1); *(uint2*)(dst +  4) = make_uint2(d0, d1);
    ilv(u.z, v.z, d0, d1); *(uint2*)(dst +  8) = make_uint2(d0, d1);
    ilv(u.w, v.w, d0, d1); *(uint2*)(dst + 12) = make_uint2(d0, d1);
  }
  __syncthreads();

  // ---- contraction 1: per wave, anchors wave*3 + {0,1,2} ----
  const unsigned int* bufd = (const unsigned int*)s_buf;
  f32x4 acc1[3][2][2] = {};
  #pragma unroll
  for (int t = 0; t < 3; ++t) {
    const int a = wave*3 + t;
    const int based = a*544 + quad*136 + lq;   // dword addr; rows n2 at stride 34
    frag_u af0, af1;
    #pragma unroll
    for (int i = 0; i < 4; ++i) {
      af0.u[i] = bufd[based + 34*i];        // c = lq
      af1.u[i] = bufd[based + 34*i + 16];   // c = 16+lq
    }
    const int k1 = (lq < 8) ? (16 + lq) : 23;     // clamped; cols>=24 discarded
    const float4 rk0 = s_rk4[a*KS + lq];
    const float4 rk1 = s_rk4[a*KS + k1];
    frag_u b0, b1;
    #pragma unroll
    for (int i = 0; i < 4; ++i) {
      const float4 rA = s_rel4[quad*8 + 2*i];
      const float4 rB = s_rel4[quad*8 + 2*i + 1];
      b0.u[i] = bfpair(wcalc(rk0, rA), wcalc(rk0, rB));
      b1.u[i] = bfpair(wcalc(rk1, rA), wcalc(rk1, rB));
    }
    acc1[t][0][0] = __builtin_amdgcn_mfma_f32_16x16x32_bf16(af0.s, b0.s, acc1[t][0][0], 0, 0, 0);
    acc1[t][0][1] = __builtin_amdgcn_mfma_f32_16x16x32_bf16(af0.s, b1.s, acc1[t][0][1], 0, 0, 0);
    acc1[t][1][0] = __builtin_amdgcn_mfma_f32_16x16x32_bf16(af1.s, b0.s, acc1[t][1][0], 0, 0, 0);
    acc1[t][1][1] = __builtin_amdgcn_mfma_f32_16x16x32_bf16(af1.s, b1.s, acc1[t][1][1], 0, 0, 0);
  }
  __syncthreads();   // all gf reads complete before nf aliases the region

  // ---- nf -> LDS bf16 [a][k*40 + c] ----
  #pragma unroll
  for (int t = 0; t < 3; ++t) {
    const int a = wave*3 + t;
    unsigned short* row = &s_buf[a*SA];
    uint2 pk;
    pk.x = bfpair(acc1[t][0][0][0], acc1[t][0][0][1]);
    pk.y = bfpair(acc1[t][0][0][2], acc1[t][0][0][3]);
    *(uint2*)&row[lq*40 + quad*4] = pk;                    // mt0, k=lq
    pk.x = bfpair(acc1[t][1][0][0], acc1[t][1][0][1]);
    pk.y = bfpair(acc1[t][1][0][2], acc1[t][1][0][3]);
    *(uint2*)&row[lq*40 + 16 + quad*4] = pk;               // mt1, k=lq
    if (lq < 8) {
      pk.x = bfpair(acc1[t][0][1][0], acc1[t][0][1][1]);
      pk.y = bfpair(acc1[t][0][1][2], acc1[t][0][1][3]);
      *(uint2*)&row[(16+lq)*40 + quad*4] = pk;             // mt0, k=16+lq
      pk.x = bfpair(acc1[t][1][1][0], acc1[t][1][1][1]);
      pk.y = bfpair(acc1[t][1][1][2], acc1[t][1][1][3]);
      *(uint2*)&row[(16+lq)*40 + 16 + quad*4] = pk;        // mt1, k=16+lq
    }
  }
  __syncthreads();

  // ---- contraction 2: out[o=64][ac=12] = Wb[64 x 768] * nf[768 x ac] ----
  const int acl = (lq < AC) ? lq : (AC - 1);      // clamp; cols 12..15 discarded
  const unsigned short* wptr = Wb + (size_t)(wave*16 + lq)*(CIN*KS) + quad*8;
  const unsigned short* nptr = &s_buf[acl*SA + quad*8];
  f32x4 accA = {0.f,0.f,0.f,0.f}, accB = {0.f,0.f,0.f,0.f};
  #pragma unroll 4
  for (int s = 0; s < 24; s += 2) {
    const short8 aw0 = *(const short8*)(wptr + s*32);
    const short8 bn0 = *(const short8*)(nptr + s*40);
    const short8 aw1 = *(const short8*)(wptr + s*32 + 32);
    const short8 bn1 = *(const short8*)(nptr + s*40 + 40);
    accA = __builtin_amdgcn_mfma_f32_16x16x32_bf16(aw0, bn0, accA, 0, 0, 0);
    accB = __builtin_amdgcn_mfma_f32_16x16x32_bf16(aw1, bn1, accB, 0, 0, 0);
  }

  if (lq < AC) {
    const int ob = wave*16 + quad*4;
    #pragma unroll
    for (int r = 0; r < 4; ++r)
      out[(size_t)(ob + r)*(P_PTS*NA) + p*NA + a0 + lq] = accA[r] + accB[r];
  }
}

// ---------------------------------------------------------------------------
extern "C" void kernel_launch(void* const* d_in, const int* in_sizes, int n_in,
                              void* d_out, int out_size, void* d_ws, size_t ws_size,
                              hipStream_t stream) {
  const float* xyz     = (const float*)d_in[0];   // [1,3,1024]
  const float* feats   = (const float*)d_in[1];   // [1,32,1024,60]
  const float* Wm      = (const float*)d_in[2];   // [64,768]
  const float* anchors = (const float*)d_in[3];   // [60,3,3]
  const float* kernels = (const float*)d_in[4];   // [24,3]
  float* out = (float*)d_out;

  // ws: Wb bf16 (98304 B) | idx (131072 B) | rk4 (23040 B) | ft bf16 (3932160 B)
  unsigned short* ws_wbf = (unsigned short*)d_ws;
  int*    ws_idx = (int*)((char*)d_ws + 98304);
  float4* ws_rk4 = (float4*)((char*)d_ws + 98304 + 131072);
  unsigned short* ws_ft = (unsigned short*)((char*)d_ws + 98304 + 131072 + 23040);

  hipLaunchKernelGGL(ball_query_kernel, dim3(P_PTS/4), dim3(256), 0, stream,
                     xyz, ws_idx);
  hipLaunchKernelGGL(transpose_kernel, dim3(P_PTS), dim3(256), 0, stream,
                     feats, ws_ft);
  hipLaunchKernelGGL(prep_kernel, dim3((COUT*CIN*KS + NA*KS + 255)/256), dim3(256), 0, stream,
                     Wm, anchors, kernels, ws_wbf, ws_rk4);
  hipLaunchKernelGGL(conv_mfma, dim3(P_PTS, NCH), dim3(256), 0, stream,
                     xyz, ws_ft, ws_wbf, ws_idx, ws_rk4, out);
}

// Round 7
// 139.578 us; speedup vs baseline: 2.3507x; 1.0427x over previous
//
#include <hip/hip_runtime.h>

typedef __attribute__((ext_vector_type(8))) short short8;
typedef __attribute__((ext_vector_type(4))) float f32x4;
typedef __attribute__((ext_vector_type(4))) unsigned int uint4v;

#define P_PTS   1024
#define NN      32
#define NA      60
#define KS      24
#define CIN     32
#define COUT    64
#define AC      12          // anchors per chunk
#define NCH     5           // 60 / 12
#define SA      968         // nf LDS anchor stride (shorts): 24*40 + 8 pad
// gf interleaved layout: short addr = a*1088 + n2*68 + c*2 + parity
//   (dword addr = a*544 + n2*34 + c ; dword = {bf16(n=2*n2), bf16(n=2*n2+1)})
#define GF_SHORTS (AC*16*68)   // 13056 shorts = 26112 B  (>= nf 11616 shorts)

union frag_u { uint4v u; short8 s; };

// full RNE float->bf16
__device__ __forceinline__ unsigned short f2bf(float f) {
  unsigned int u = __float_as_uint(f);
  u += 0x7FFFu + ((u >> 16) & 1u);
  return (unsigned short)(u >> 16);
}
// fast pack: two floats -> bf16x2 (round-half-up)
__device__ __forceinline__ unsigned int bfpair(float a, float b) {
  unsigned int ua = __float_as_uint(a) + 0x8000u;
  unsigned int ub = __float_as_uint(b) + 0x8000u;
  return __builtin_amdgcn_perm(ub, ua, 0x07060302u);  // {hi16(b), hi16(a)}
}
// interleave low/high shorts of two dwords: lo = {u.s0, v.s0}, hi = {u.s1, v.s1}
__device__ __forceinline__ void ilv(unsigned int u, unsigned int v,
                                    unsigned int& lo, unsigned int& hi) {
  lo = __builtin_amdgcn_perm(v, u, 0x05040100u);
  hi = __builtin_amdgcn_perm(v, u, 0x07060302u);
}

// w = relu(1 - d2/0.16) = max(0, (1-6.25|rk|^2) - 6.25|rel|^2 + 12.5<rk,rel>)
__device__ __forceinline__ float wcalc(const float4 rk, const float4 rl) {
  return fmaxf(0.0f, fmaf(rk.x, rl.x, fmaf(rk.y, rl.y, fmaf(rk.z, rl.z, rk.w + rl.w))));
}

// ---------------------------------------------------------------------------
// Fused setup kernel — STRICTLY DISJOINT block roles (unlike failed R5 where
// every block ran transpose plus a second role):
//   blocks    0..255  : ball query (4 query points each, one per wave)
//   blocks 256..1279  : transpose feats [c][p][a] fp32 -> ft [p][a][c] bf16
//   blocks 1280..1471 : W -> bf16 permuted [o][k][c]
//   blocks 1472..1477 : rotated kernel points rk4
// ---------------------------------------------------------------------------
#define SETUP_BLOCKS 1478

__global__ __launch_bounds__(256) void setup_kernel(
    const float* __restrict__ xyz, const float* __restrict__ feats,
    const float* __restrict__ Wm, const float* __restrict__ anchors,
    const float* __restrict__ kernels, int* __restrict__ ws_idx,
    unsigned short* __restrict__ ws_ft, unsigned short* __restrict__ ws_wbf,
    float4* __restrict__ ws_rk4)
{
  const int b   = blockIdx.x;
  const int tid = threadIdx.x;

  __shared__ float sx[P_PTS], sy[P_PTS], sz[P_PTS], sq[P_PTS];
  __shared__ int s_loc[4][NN];
  __shared__ unsigned short s_t[CIN*NA];   // [c][a]

  if (b < 256) {
    // ---- ball query, one query per wave ----
    for (int i = tid; i < P_PTS; i += 256) {
      float x = xyz[i], y = xyz[P_PTS + i], z = xyz[2*P_PTS + i];
      sx[i] = x; sy[i] = y; sz[i] = z;
      sq[i] = x*x + y*y + z*z;
    }
    __syncthreads();
    const int wave = tid >> 6, lane = tid & 63;
    const int q = b*4 + wave;
    const float xq = sx[q], yq = sy[q], zq = sz[q], sqq = sq[q];
    int cnt = 0;
    for (int jb = 0; jb < P_PTS; jb += 64) {
      const int j = jb + lane;
      const float d2 = sqq + sq[j] - 2.0f*(xq*sx[j] + yq*sy[j] + zq*sz[j]);
      const bool pred = d2 < 1.0f;
      const unsigned long long mask = __ballot(pred);
      if (pred) {
        const int slot = cnt + __popcll(mask & ((1ull << lane) - 1ull));
        if (slot < NN) s_loc[wave][slot] = j;
      }
      cnt += (int)__popcll(mask);
      if (cnt >= NN) break;
    }
    __syncthreads();
    const int cntc = cnt < NN ? cnt : NN;
    if (lane >= cntc && lane < NN) s_loc[wave][lane] = s_loc[wave][0];
    __syncthreads();
    if (lane < NN) ws_idx[q*NN + lane] = s_loc[wave][lane];
  } else if (b < 1280) {
    // ---- transpose for p = b - 256 ----
    const int p = b - 256;
    for (int e = tid; e < CIN*NA; e += 256) {
      const int c = e / NA, a = e - c*NA;
      s_t[e] = f2bf(feats[c*(P_PTS*NA) + p*NA + a]);
    }
    __syncthreads();
    unsigned int* out32 = (unsigned int*)(ws_ft + p*(CIN*NA));
    for (int e = tid; e < (CIN*NA)/2; e += 256) {
      const int a = e >> 4, cu = e & 15;
      const unsigned int lo = s_t[(2*cu    )*NA + a];
      const unsigned int hi = s_t[(2*cu + 1)*NA + a];
      out32[a*16 + cu] = lo | (hi << 16);
    }
  } else if (b < 1472) {
    // ---- W convert: bf16 permuted [o][k][c] ----
    const int t = (b - 1280)*256 + tid;      // < 49152 = COUT*CIN*KS
    const int o = t / (CIN*KS), r = t - o*(CIN*KS);
    const int k = r >> 5, c = r & 31;
    ws_wbf[t] = f2bf(Wm[o*(CIN*KS) + c*KS + k]);
  } else {
    // ---- rk4 ----
    const int u = (b - 1472)*256 + tid;
    if (u < NA*KS) {
      const int a = u / KS, k = u - a*KS;
      const float rx = anchors[a*9+0]*kernels[k*3+0] + anchors[a*9+1]*kernels[k*3+1] + anchors[a*9+2]*kernels[k*3+2];
      const float ry = anchors[a*9+3]*kernels[k*3+0] + anchors[a*9+4]*kernels[k*3+1] + anchors[a*9+5]*kernels[k*3+2];
      const float rz = anchors[a*9+6]*kernels[k*3+0] + anchors[a*9+7]*kernels[k*3+1] + anchors[a*9+8]*kernels[k*3+2];
      ws_rk4[u] = make_float4(12.5f*rx, 12.5f*ry, 12.5f*rz,
                              1.0f - 6.25f*(rx*rx + ry*ry + rz*rz));
    }
  }
}

// ---------------------------------------------------------------------------
// Main fused kernel — byte-identical to R6's passing version.
// Block = (point p, chunk of 12 anchors).
// ---------------------------------------------------------------------------
__global__ __launch_bounds__(256, 4) void conv_mfma(
    const float* __restrict__ xyz, const unsigned short* __restrict__ ft,
    const unsigned short* __restrict__ Wb, const int* __restrict__ g_idx,
    const float4* __restrict__ g_rk4, float* __restrict__ out)
{
  const int p    = blockIdx.x;
  const int a0   = blockIdx.y * AC;
  const int tid  = threadIdx.x;
  const int wave = tid >> 6;
  const int lane = tid & 63;
  const int quad = lane >> 4;
  const int lq   = lane & 15;

  __shared__ __align__(16) unsigned short s_buf[GF_SHORTS];  // 26112 B, aliased by nf
  __shared__ __align__(16) float4 s_rel4[NN];   // (rx,ry,rz,-6.25*|r|^2)
  __shared__ __align__(16) float4 s_rk4[AC*KS];
  __shared__ int s_idx[NN];

  // ---- phase 0 ----
  if (tid < NN) {
    const int j = g_idx[p*NN + tid];
    s_idx[tid] = j;
    const float rx = xyz[j]           - xyz[p];
    const float ry = xyz[P_PTS + j]   - xyz[P_PTS + p];
    const float rz = xyz[2*P_PTS + j] - xyz[2*P_PTS + p];
    s_rel4[tid] = make_float4(rx, ry, rz, -6.25f*(rx*rx + ry*ry + rz*rz));
  }
  for (int e = tid; e < AC*KS; e += 256) s_rk4[e] = g_rk4[a0*KS + e];
  __syncthreads();

  // ---- staging: thread owns (n-pair np, c-chunk ce), 3 anchors ----
  const int np = (tid >> 2) & 15;
  const int ce = tid & 3;
  const int i0 = s_idx[2*np];
  const int i1 = s_idx[2*np + 1];
  const unsigned short* ft0 = ft + (size_t)i0*(CIN*NA) + a0*CIN + ce*8;
  const unsigned short* ft1 = ft + (size_t)i1*(CIN*NA) + a0*CIN + ce*8;
  #pragma unroll
  for (int i = 0; i < 3; ++i) {
    const int a = i*4 + wave;
    const uint4 u = *(const uint4*)(ft0 + a*CIN);
    const uint4 v = *(const uint4*)(ft1 + a*CIN);
    unsigned short* dst = &s_buf[a*1088 + np*68 + ce*16];
    unsigned int d0, d1;
    ilv(u.x, v.x, d0, d1); *(uint2*)(dst +  0) = make_uint2(d0, d1);
    ilv(u.y, v.y, d0, d1); *(uint2*)(dst +  4) = make_uint2(d0, d1);
    ilv(u.z, v.z, d0, d1); *(uint2*)(dst +  8) = make_uint2(d0, d1);
    ilv(u.w, v.w, d0, d1); *(uint2*)(dst + 12) = make_uint2(d0, d1);
  }
  __syncthreads();

  // ---- contraction 1: per wave, anchors wave*3 + {0,1,2} ----
  const unsigned int* bufd = (const unsigned int*)s_buf;
  f32x4 acc1[3][2][2] = {};
  #pragma unroll
  for (int t = 0; t < 3; ++t) {
    const int a = wave*3 + t;
    const int based = a*544 + quad*136 + lq;   // dword addr; rows n2 at stride 34
    frag_u af0, af1;
    #pragma unroll
    for (int i = 0; i < 4; ++i) {
      af0.u[i] = bufd[based + 34*i];        // c = lq
      af1.u[i] = bufd[based + 34*i + 16];   // c = 16+lq
    }
    const int k1 = (lq < 8) ? (16 + lq) : 23;     // clamped; cols>=24 discarded
    const float4 rk0 = s_rk4[a*KS + lq];
    const float4 rk1 = s_rk4[a*KS + k1];
    frag_u b0, b1;
    #pragma unroll
    for (int i = 0; i < 4; ++i) {
      const float4 rA = s_rel4[quad*8 + 2*i];
      const float4 rB = s_rel4[quad*8 + 2*i + 1];
      b0.u[i] = bfpair(wcalc(rk0, rA), wcalc(rk0, rB));
      b1.u[i] = bfpair(wcalc(rk1, rA), wcalc(rk1, rB));
    }
    acc1[t][0][0] = __builtin_amdgcn_mfma_f32_16x16x32_bf16(af0.s, b0.s, acc1[t][0][0], 0, 0, 0);
    acc1[t][0][1] = __builtin_amdgcn_mfma_f32_16x16x32_bf16(af0.s, b1.s, acc1[t][0][1], 0, 0, 0);
    acc1[t][1][0] = __builtin_amdgcn_mfma_f32_16x16x32_bf16(af1.s, b0.s, acc1[t][1][0], 0, 0, 0);
    acc1[t][1][1] = __builtin_amdgcn_mfma_f32_16x16x32_bf16(af1.s, b1.s, acc1[t][1][1], 0, 0, 0);
  }
  __syncthreads();   // all gf reads complete before nf aliases the region

  // ---- nf -> LDS bf16 [a][k*40 + c] ----
  #pragma unroll
  for (int t = 0; t < 3; ++t) {
    const int a = wave*3 + t;
    unsigned short* row = &s_buf[a*SA];
    uint2 pk;
    pk.x = bfpair(acc1[t][0][0][0], acc1[t][0][0][1]);
    pk.y = bfpair(acc1[t][0][0][2], acc1[t][0][0][3]);
    *(uint2*)&row[lq*40 + quad*4] = pk;                    // mt0, k=lq
    pk.x = bfpair(acc1[t][1][0][0], acc1[t][1][0][1]);
    pk.y = bfpair(acc1[t][1][0][2], acc1[t][1][0][3]);
    *(uint2*)&row[lq*40 + 16 + quad*4] = pk;               // mt1, k=lq
    if (lq < 8) {
      pk.x = bfpair(acc1[t][0][1][0], acc1[t][0][1][1]);
      pk.y = bfpair(acc1[t][0][1][2], acc1[t][0][1][3]);
      *(uint2*)&row[(16+lq)*40 + quad*4] = pk;             // mt0, k=16+lq
      pk.x = bfpair(acc1[t][1][1][0], acc1[t][1][1][1]);
      pk.y = bfpair(acc1[t][1][1][2], acc1[t][1][1][3]);
      *(uint2*)&row[(16+lq)*40 + 16 + quad*4] = pk;        // mt1, k=16+lq
    }
  }
  __syncthreads();

  // ---- contraction 2: out[o=64][ac=12] = Wb[64 x 768] * nf[768 x ac] ----
  const int acl = (lq < AC) ? lq : (AC - 1);      // clamp; cols 12..15 discarded
  const unsigned short* wptr = Wb + (size_t)(wave*16 + lq)*(CIN*KS) + quad*8;
  const unsigned short* nptr = &s_buf[acl*SA + quad*8];
  f32x4 accA = {0.f,0.f,0.f,0.f}, accB = {0.f,0.f,0.f,0.f};
  #pragma unroll 4
  for (int s = 0; s < 24; s += 2) {
    const short8 aw0 = *(const short8*)(wptr + s*32);
    const short8 bn0 = *(const short8*)(nptr + s*40);
    const short8 aw1 = *(const short8*)(wptr + s*32 + 32);
    const short8 bn1 = *(const short8*)(nptr + s*40 + 40);
    accA = __builtin_amdgcn_mfma_f32_16x16x32_bf16(aw0, bn0, accA, 0, 0, 0);
    accB = __builtin_amdgcn_mfma_f32_16x16x32_bf16(aw1, bn1, accB, 0, 0, 0);
  }

  if (lq < AC) {
    const int ob = wave*16 + quad*4;
    #pragma unroll
    for (int r = 0; r < 4; ++r)
      out[(size_t)(ob + r)*(P_PTS*NA) + p*NA + a0 + lq] = accA[r] + accB[r];
  }
}

// ---------------------------------------------------------------------------
extern "C" void kernel_launch(void* const* d_in, const int* in_sizes, int n_in,
                              void* d_out, int out_size, void* d_ws, size_t ws_size,
                              hipStream_t stream) {
  const float* xyz     = (const float*)d_in[0];   // [1,3,1024]
  const float* feats   = (const float*)d_in[1];   // [1,32,1024,60]
  const float* Wm      = (const float*)d_in[2];   // [64,768]
  const float* anchors = (const float*)d_in[3];   // [60,3,3]
  const float* kernels = (const float*)d_in[4];   // [24,3]
  float* out = (float*)d_out;

  // ws: Wb bf16 (98304 B) | idx (131072 B) | rk4 (23040 B) | ft bf16 (3932160 B)
  unsigned short* ws_wbf = (unsigned short*)d_ws;
  int*    ws_idx = (int*)((char*)d_ws + 98304);
  float4* ws_rk4 = (float4*)((char*)d_ws + 98304 + 131072);
  unsigned short* ws_ft = (unsigned short*)((char*)d_ws + 98304 + 131072 + 23040);

  hipLaunchKernelGGL(setup_kernel, dim3(SETUP_BLOCKS), dim3(256), 0, stream,
                     xyz, feats, Wm, anchors, kernels, ws_idx, ws_ft, ws_wbf, ws_rk4);
  hipLaunchKernelGGL(conv_mfma, dim3(P_PTS, NCH), dim3(256), 0, stream,
                     xyz, ws_ft, ws_wbf, ws_idx, ws_rk4, out);
}

// Round 8
// 109.375 us; speedup vs baseline: 2.9999x; 1.2761x over previous
//
#include <hip/hip_runtime.h>

typedef __attribute__((ext_vector_type(8))) short short8;
typedef __attribute__((ext_vector_type(4))) float f32x4;
typedef __attribute__((ext_vector_type(4))) unsigned int uint4v;

#define P_PTS   1024
#define NN      32
#define NA      60
#define KS      24
#define CIN     32
#define COUT    64
#define AC      12          // anchors per chunk
#define NCH     5           // 60 / 12
#define SA      968         // nf LDS anchor stride (shorts): 24*40 + 8 pad
// gf interleaved layout: short addr = a*1152 + n2*72 + c*2 + parity
//   (dword addr = a*576 + n2*36 + c ; dword = {bf16(n=2*n2), bf16(n=2*n2+1)})
//   row stride 72 shorts = 144 B: 16B-aligned (b128 stores), quad-stride 144
//   dwords == 16 mod 32 -> exactly 2-way bank aliasing on frag reads (free).
#define GF_SHORTS (AC*16*72)   // 13824 shorts = 27648 B  (>= nf 11616 shorts)

union frag_u { uint4v u; short8 s; };

// full RNE float->bf16
__device__ __forceinline__ unsigned short f2bf(float f) {
  unsigned int u = __float_as_uint(f);
  u += 0x7FFFu + ((u >> 16) & 1u);
  return (unsigned short)(u >> 16);
}
// fast pack: two floats -> bf16x2 (round-half-up)
__device__ __forceinline__ unsigned int bfpair(float a, float b) {
  unsigned int ua = __float_as_uint(a) + 0x8000u;
  unsigned int ub = __float_as_uint(b) + 0x8000u;
  return __builtin_amdgcn_perm(ub, ua, 0x07060302u);  // {hi16(b), hi16(a)}
}
// interleave low/high shorts of two dwords: lo = {u.s0, v.s0}, hi = {u.s1, v.s1}
__device__ __forceinline__ void ilv(unsigned int u, unsigned int v,
                                    unsigned int& lo, unsigned int& hi) {
  lo = __builtin_amdgcn_perm(v, u, 0x05040100u);
  hi = __builtin_amdgcn_perm(v, u, 0x07060302u);
}

// w = relu(1 - d2/0.16) = max(0, (1-6.25|rk|^2) - 6.25|rel|^2 + 12.5<rk,rel>)
__device__ __forceinline__ float wcalc(const float4 rk, const float4 rl) {
  return fmaxf(0.0f, fmaf(rk.x, rl.x, fmaf(rk.y, rl.y, fmaf(rk.z, rl.z, rk.w + rl.w))));
}

// ---------------------------------------------------------------------------
// Fused setup kernel — strictly disjoint block roles:
//   blocks    0..255  : ball query (4 query points each, one per wave)
//   blocks 256..1279  : transpose feats [c][p][a] fp32 -> ft [p][a][c] bf16
//   blocks 1280..1303 : W -> bf16 in MFMA-frag streaming order
//   blocks 1304..1309 : rotated kernel points rk4
// ---------------------------------------------------------------------------
#define SETUP_BLOCKS 1310

__global__ __launch_bounds__(256) void setup_kernel(
    const float* __restrict__ xyz, const float* __restrict__ feats,
    const float* __restrict__ Wm, const float* __restrict__ anchors,
    const float* __restrict__ kernels, int* __restrict__ ws_idx,
    unsigned short* __restrict__ ws_ft, unsigned short* __restrict__ ws_wbf,
    float4* __restrict__ ws_rk4)
{
  const int b   = blockIdx.x;
  const int tid = threadIdx.x;

  __shared__ float sx[P_PTS], sy[P_PTS], sz[P_PTS], sq[P_PTS];
  __shared__ int s_loc[4][NN];
  __shared__ unsigned short s_t[CIN*NA];   // [c][a]

  if (b < 256) {
    // ---- ball query, one query per wave ----
    for (int i = tid; i < P_PTS; i += 256) {
      float x = xyz[i], y = xyz[P_PTS + i], z = xyz[2*P_PTS + i];
      sx[i] = x; sy[i] = y; sz[i] = z;
      sq[i] = x*x + y*y + z*z;
    }
    __syncthreads();
    const int wave = tid >> 6, lane = tid & 63;
    const int q = b*4 + wave;
    const float xq = sx[q], yq = sy[q], zq = sz[q], sqq = sq[q];
    int cnt = 0;
    for (int jb = 0; jb < P_PTS; jb += 64) {
      const int j = jb + lane;
      const float d2 = sqq + sq[j] - 2.0f*(xq*sx[j] + yq*sy[j] + zq*sz[j]);
      const bool pred = d2 < 1.0f;
      const unsigned long long mask = __ballot(pred);
      if (pred) {
        const int slot = cnt + __popcll(mask & ((1ull << lane) - 1ull));
        if (slot < NN) s_loc[wave][slot] = j;
      }
      cnt += (int)__popcll(mask);
      if (cnt >= NN) break;
    }
    __syncthreads();
    const int cntc = cnt < NN ? cnt : NN;
    if (lane >= cntc && lane < NN) s_loc[wave][lane] = s_loc[wave][0];
    __syncthreads();
    if (lane < NN) ws_idx[q*NN + lane] = s_loc[wave][lane];
  } else if (b < 1280) {
    // ---- transpose for p = b - 256 ----
    const int p = b - 256;
    for (int e = tid; e < CIN*NA; e += 256) {
      const int c = e / NA, a = e - c*NA;
      s_t[e] = f2bf(feats[c*(P_PTS*NA) + p*NA + a]);
    }
    __syncthreads();
    unsigned int* out32 = (unsigned int*)(ws_ft + p*(CIN*NA));
    for (int e = tid; e < (CIN*NA)/2; e += 256) {
      const int a = e >> 4, cu = e & 15;
      const unsigned int lo = s_t[(2*cu    )*NA + a];
      const unsigned int hi = s_t[(2*cu + 1)*NA + a];
      out32[a*16 + cu] = lo | (hi << 16);
    }
  } else if (b < 1304) {
    // ---- W -> bf16, MFMA-frag streaming order:
    //      Wf[(((w*24)+s)*64 + lane)*8 + j] = W[o=w*16+lq][c=quad*8+j][k=s]
    const int t = (b - 1280)*256 + tid;      // < 6144
    const int w = t / 1536;
    const int r = t - w*1536;
    const int s = r >> 6;
    const int lane = r & 63;
    const int quad = lane >> 4, lq = lane & 15;
    const int o = w*16 + lq;
    unsigned short h[8];
    #pragma unroll
    for (int j = 0; j < 8; ++j)
      h[j] = f2bf(Wm[o*(CIN*KS) + (quad*8 + j)*KS + s]);
    *(uint4*)(ws_wbf + (size_t)t*8) = *(const uint4*)h;
  } else {
    // ---- rk4 ----
    const int u = (b - 1304)*256 + tid;
    if (u < NA*KS) {
      const int a = u / KS, k = u - a*KS;
      const float rx = anchors[a*9+0]*kernels[k*3+0] + anchors[a*9+1]*kernels[k*3+1] + anchors[a*9+2]*kernels[k*3+2];
      const float ry = anchors[a*9+3]*kernels[k*3+0] + anchors[a*9+4]*kernels[k*3+1] + anchors[a*9+5]*kernels[k*3+2];
      const float rz = anchors[a*9+6]*kernels[k*3+0] + anchors[a*9+7]*kernels[k*3+1] + anchors[a*9+8]*kernels[k*3+2];
      ws_rk4[u] = make_float4(12.5f*rx, 12.5f*ry, 12.5f*rz,
                              1.0f - 6.25f*(rx*rx + ry*ry + rz*rz));
    }
  }
}

// ---------------------------------------------------------------------------
// Main fused kernel. Block = (point p, chunk of 12 anchors).
// gf staged coalesced with neighbor-pair interleaving (b128 stores, b32 frag
// reads, 2-way banks = free); w in registers; nf aliases gf; c2 A-operand
// streams from frag-ordered Wf (fully dense 1 KB/instr loads).
// ---------------------------------------------------------------------------
__global__ __launch_bounds__(256, 4) void conv_mfma(
    const float* __restrict__ xyz, const unsigned short* __restrict__ ft,
    const unsigned short* __restrict__ Wf, const int* __restrict__ g_idx,
    const float4* __restrict__ g_rk4, float* __restrict__ out)
{
  const int p    = blockIdx.x;
  const int a0   = blockIdx.y * AC;
  const int tid  = threadIdx.x;
  const int wave = tid >> 6;
  const int lane = tid & 63;
  const int quad = lane >> 4;
  const int lq   = lane & 15;

  __shared__ __align__(16) unsigned short s_buf[GF_SHORTS];  // 27648 B, aliased by nf
  __shared__ __align__(16) float4 s_rel4[NN];   // (rx,ry,rz,-6.25*|r|^2)
  __shared__ __align__(16) float4 s_rk4[AC*KS];
  __shared__ int s_idx[NN];

  // ---- phase 0 ----
  if (tid < NN) {
    const int j = g_idx[p*NN + tid];
    s_idx[tid] = j;
    const float rx = xyz[j]           - xyz[p];
    const float ry = xyz[P_PTS + j]   - xyz[P_PTS + p];
    const float rz = xyz[2*P_PTS + j] - xyz[2*P_PTS + p];
    s_rel4[tid] = make_float4(rx, ry, rz, -6.25f*(rx*rx + ry*ry + rz*rz));
  }
  for (int e = tid; e < AC*KS; e += 256) s_rk4[e] = g_rk4[a0*KS + e];
  __syncthreads();

  // ---- staging: thread owns (n-pair np, c-chunk ce), 3 anchors ----
  const int np = (tid >> 2) & 15;
  const int ce = tid & 3;
  const int i0 = s_idx[2*np];
  const int i1 = s_idx[2*np + 1];
  const unsigned short* ft0 = ft + (size_t)i0*(CIN*NA) + a0*CIN + ce*8;
  const unsigned short* ft1 = ft + (size_t)i1*(CIN*NA) + a0*CIN + ce*8;
  #pragma unroll
  for (int i = 0; i < 3; ++i) {
    const int a = i*4 + wave;
    const uint4 u = *(const uint4*)(ft0 + a*CIN);
    const uint4 v = *(const uint4*)(ft1 + a*CIN);
    unsigned short* dst = &s_buf[a*1152 + np*72 + ce*16];
    uint4v w0, w1;
    unsigned int d0, d1;
    ilv(u.x, v.x, d0, d1); w0[0] = d0; w0[1] = d1;
    ilv(u.y, v.y, d0, d1); w0[2] = d0; w0[3] = d1;
    ilv(u.z, v.z, d0, d1); w1[0] = d0; w1[1] = d1;
    ilv(u.w, v.w, d0, d1); w1[2] = d0; w1[3] = d1;
    *(uint4v*)(dst)     = w0;
    *(uint4v*)(dst + 8) = w1;
  }
  __syncthreads();

  // ---- contraction 1: per wave, anchors wave*3 + {0,1,2} ----
  const unsigned int* bufd = (const unsigned int*)s_buf;
  f32x4 acc1[3][2][2] = {};
  #pragma unroll
  for (int t = 0; t < 3; ++t) {
    const int a = wave*3 + t;
    const int based = a*576 + quad*144 + lq;   // dword addr; rows n2 at stride 36
    frag_u af0, af1;
    #pragma unroll
    for (int i = 0; i < 4; ++i) {
      af0.u[i] = bufd[based + 36*i];        // c = lq
      af1.u[i] = bufd[based + 36*i + 16];   // c = 16+lq
    }
    const int k1 = (lq < 8) ? (16 + lq) : 23;     // clamped; cols>=24 discarded
    const float4 rk0 = s_rk4[a*KS + lq];
    const float4 rk1 = s_rk4[a*KS + k1];
    frag_u b0, b1;
    #pragma unroll
    for (int i = 0; i < 4; ++i) {
      const float4 rA = s_rel4[quad*8 + 2*i];
      const float4 rB = s_rel4[quad*8 + 2*i + 1];
      b0.u[i] = bfpair(wcalc(rk0, rA), wcalc(rk0, rB));
      b1.u[i] = bfpair(wcalc(rk1, rA), wcalc(rk1, rB));
    }
    acc1[t][0][0] = __builtin_amdgcn_mfma_f32_16x16x32_bf16(af0.s, b0.s, acc1[t][0][0], 0, 0, 0);
    acc1[t][0][1] = __builtin_amdgcn_mfma_f32_16x16x32_bf16(af0.s, b1.s, acc1[t][0][1], 0, 0, 0);
    acc1[t][1][0] = __builtin_amdgcn_mfma_f32_16x16x32_bf16(af1.s, b0.s, acc1[t][1][0], 0, 0, 0);
    acc1[t][1][1] = __builtin_amdgcn_mfma_f32_16x16x32_bf16(af1.s, b1.s, acc1[t][1][1], 0, 0, 0);
  }
  __syncthreads();   // all gf reads complete before nf aliases the region

  // ---- nf -> LDS bf16 [a][k*40 + c] ----
  #pragma unroll
  for (int t = 0; t < 3; ++t) {
    const int a = wave*3 + t;
    unsigned short* row = &s_buf[a*SA];
    uint2 pk;
    pk.x = bfpair(acc1[t][0][0][0], acc1[t][0][0][1]);
    pk.y = bfpair(acc1[t][0][0][2], acc1[t][0][0][3]);
    *(uint2*)&row[lq*40 + quad*4] = pk;                    // mt0, k=lq
    pk.x = bfpair(acc1[t][1][0][0], acc1[t][1][0][1]);
    pk.y = bfpair(acc1[t][1][0][2], acc1[t][1][0][3]);
    *(uint2*)&row[lq*40 + 16 + quad*4] = pk;               // mt1, k=lq
    if (lq < 8) {
      pk.x = bfpair(acc1[t][0][1][0], acc1[t][0][1][1]);
      pk.y = bfpair(acc1[t][0][1][2], acc1[t][0][1][3]);
      *(uint2*)&row[(16+lq)*40 + quad*4] = pk;             // mt0, k=16+lq
      pk.x = bfpair(acc1[t][1][1][0], acc1[t][1][1][1]);
      pk.y = bfpair(acc1[t][1][1][2], acc1[t][1][1][3]);
      *(uint2*)&row[(16+lq)*40 + 16 + quad*4] = pk;        // mt1, k=16+lq
    }
  }
  __syncthreads();

  // ---- contraction 2: out[o=64][ac=12] = W[64 x 768] * nf[768 x ac] ----
  // A streams from frag-ordered Wf: per load, 64 lanes x 16 B contiguous.
  const int acl = (lq < AC) ? lq : (AC - 1);      // clamp; cols 12..15 discarded
  const unsigned short* wptr = Wf + (size_t)wave*(24*512) + lane*8;
  const unsigned short* nptr = &s_buf[acl*SA + quad*8];
  f32x4 accA = {0.f,0.f,0.f,0.f}, accB = {0.f,0.f,0.f,0.f};
  #pragma unroll 4
  for (int s = 0; s < 24; s += 2) {
    const short8 aw0 = *(const short8*)(wptr + s*512);
    const short8 bn0 = *(const short8*)(nptr + s*40);
    const short8 aw1 = *(const short8*)(wptr + s*512 + 512);
    const short8 bn1 = *(const short8*)(nptr + s*40 + 40);
    accA = __builtin_amdgcn_mfma_f32_16x16x32_bf16(aw0, bn0, accA, 0, 0, 0);
    accB = __builtin_amdgcn_mfma_f32_16x16x32_bf16(aw1, bn1, accB, 0, 0, 0);
  }

  if (lq < AC) {
    const int ob = wave*16 + quad*4;
    #pragma unroll
    for (int r = 0; r < 4; ++r)
      out[(size_t)(ob + r)*(P_PTS*NA) + p*NA + a0 + lq] = accA[r] + accB[r];
  }
}

// ---------------------------------------------------------------------------
extern "C" void kernel_launch(void* const* d_in, const int* in_sizes, int n_in,
                              void* d_out, int out_size, void* d_ws, size_t ws_size,
                              hipStream_t stream) {
  const float* xyz     = (const float*)d_in[0];   // [1,3,1024]
  const float* feats   = (const float*)d_in[1];   // [1,32,1024,60]
  const float* Wm      = (const float*)d_in[2];   // [64,768]
  const float* anchors = (const float*)d_in[3];   // [60,3,3]
  const float* kernels = (const float*)d_in[4];   // [24,3]
  float* out = (float*)d_out;

  // ws: Wf bf16 (98304 B) | idx (131072 B) | rk4 (23040 B) | ft bf16 (3932160 B)
  unsigned short* ws_wbf = (unsigned short*)d_ws;
  int*    ws_idx = (int*)((char*)d_ws + 98304);
  float4* ws_rk4 = (float4*)((char*)d_ws + 98304 + 131072);
  unsigned short* ws_ft = (unsigned short*)((char*)d_ws + 98304 + 131072 + 23040);

  hipLaunchKernelGGL(setup_kernel, dim3(SETUP_BLOCKS), dim3(256), 0, stream,
                     xyz, feats, Wm, anchors, kernels, ws_idx, ws_ft, ws_wbf, ws_rk4);
  hipLaunchKernelGGL(conv_mfma, dim3(P_PTS, NCH), dim3(256), 0, stream,
                     xyz, ws_ft, ws_wbf, ws_idx, ws_rk4, out);
}